// Round 2
// baseline (1179.960 us; speedup 1.0000x reference)
//
#include <hip/hip_runtime.h>

#define NB 2048
#define HDM 64
#define NLAY 5

__device__ __forceinline__ float sigmoidf_(float x){ return 1.f/(1.f+__expf(-x)); }
__device__ __forceinline__ float tanhfast_(float x){
  x = fminf(fmaxf(x, -15.f), 15.f);
  float e = __expf(2.f*x);
  return (e-1.f)/(e+1.f);
}

// ---------------- Kernel: time-embedding + GEMM1 K-split partials + zero accumulators ---------
// grid 512 x 256. TE: rows blk*4..+3.  GEMM1: rowgroup = blk>>2 (16 rows), K-quarter = blk&3.
__global__ __launch_bounds__(256) void k_pre(
    const float* __restrict__ x, const float* __restrict__ tt,
    const float* __restrict__ freqs,
    const float* __restrict__ fc1W, const float* __restrict__ fc1b,
    const float* __restrict__ fc2W, const float* __restrict__ fc2b,
    const float* __restrict__ tprojW, const float* __restrict__ tprojb,
    const float* __restrict__ nodeW,
    float* __restrict__ h0p, float* __restrict__ htime,
    float* __restrict__ zero_region)   // hsum(320) + bnacc(1920) contiguous
{
  __shared__ float xs[16*256];
  __shared__ float tb0[256];
  __shared__ float tb1[256];
  const int t = threadIdx.x, blk = blockIdx.x;
  const int r = t>>6, c = t&63;

  if (blk == 0){
    for (int i = t; i < 320 + 1920; i += 256) zero_region[i] = 0.f;
  }

  // ---- time embedding for rows blk*4 + r ----
  {
    const int row = blk*4 + r;
    const float tv = tt[row];
    float te[16];
    #pragma unroll
    for (int j=0;j<8;++j){
      float sv, cv;
      __sincosf(6.28318530717958647692f*tv*freqs[j], &sv, &cv);
      te[j]=sv; te[j+8]=cv;
    }
    float a = fc1b[c];
    #pragma unroll
    for (int j=0;j<16;++j) a += te[j]*fc1W[j*64+c];
    tb0[t] = a*sigmoidf_(a);          // silu
    __syncthreads();
    float b2 = fc2b[c];
    for (int k=0;k<64;++k) b2 += tb0[r*64+k]*fc2W[k*64+c];
    tb1[t] = b2;
    __syncthreads();
    float hti = tprojb[c];
    for (int k=0;k<64;++k) hti += tb1[r*64+k]*tprojW[k*64+c];
    htime[row*64+c] = hti;
  }

  // ---- GEMM1 partial: h0p[kq][rows0..rows0+15][64] ----
  const int rg = blk>>2, kq = blk&3;
  const int rows0 = rg*16, k0 = kq*1024;
  const int cq = t&15, rr = t>>4;
  float4 acc; acc.x=0.f; acc.y=0.f; acc.z=0.f; acc.w=0.f;
  for (int ch=0; ch<4; ++ch){
    __syncthreads();
    const int kb = k0 + ch*256;
    #pragma unroll
    for (int i=0;i<4;++i){
      int fi = t + 256*i;
      int xr = fi>>6, kk = (fi&63)<<2;
      *(float4*)&xs[xr*256+kk] = *(const float4*)&x[(size_t)(rows0+xr)*4096 + kb + kk];
    }
    __syncthreads();
    #pragma unroll 4
    for (int k=0;k<256;++k){
      float4 w = *(const float4*)&nodeW[(size_t)(kb+k)*64 + 4*cq];
      float xv = xs[rr*256+k];
      acc.x += xv*w.x; acc.y += xv*w.y; acc.z += xv*w.z; acc.w += xv*w.w;
    }
  }
  *(float4*)&h0p[(size_t)kq*(NB*HDM) + (rows0+rr)*64 + 4*cq] = acc;
}

// ---------------- Kernel: assemble h (node proj + time cat + PE cat) ----------------
__global__ __launch_bounds__(256) void k_assemble(
    const float* __restrict__ h0p, const float* __restrict__ htime,
    const float* __restrict__ nodeb,
    const float* __restrict__ tcatW, const float* __restrict__ tcatb,
    const float* __restrict__ penb, const float* __restrict__ pelW,
    const float* __restrict__ pelb,
    const float* __restrict__ catW, const float* __restrict__ catb,
    float* __restrict__ hbuf)
{
  __shared__ float sa[256];
  __shared__ float sb[256];
  __shared__ float cvec[64];
  const int t = threadIdx.x, blk = blockIdx.x;
  const int r = t>>6, c = t&63;
  const int row = blk*4 + r;

  if (r==0){
    float pl[16];
    #pragma unroll
    for (int j=0;j<16;++j){
      float a = pelb[j];
      for (int w=0;w<20;++w) a += penb[w]*pelW[w*16+j];
      pl[j]=a;
    }
    float a = catb[c];
    #pragma unroll
    for (int j=0;j<16;++j) a += pl[j]*catW[(64+j)*64+c];
    cvec[c]=a;
  }
  float h0 = nodeb[c];
  #pragma unroll
  for (int q=0;q<4;++q) h0 += h0p[(size_t)q*(NB*HDM) + row*64 + c];
  sa[t] = h0;
  sb[t] = htime[row*64+c];
  __syncthreads();
  float a = tcatb[c];
  for (int k=0;k<64;++k) a += sa[r*64+k]*tcatW[k*64+c];
  for (int k=0;k<64;++k) a += sb[r*64+k]*tcatW[(64+k)*64+c];
  __syncthreads();
  sa[t] = a;
  __syncthreads();
  float hv = cvec[c];
  for (int k=0;k<64;++k) hv += sa[r*64+k]*catW[k*64+c];
  hbuf[row*64+c] = hv;
}

// ---------------- Kernel A (per layer): [bn3 of prev] + hsum + gh + qkv ----------------
__global__ __launch_bounds__(256) void k_A(
    const float* __restrict__ smlp,       // prev layer pre-bn3 (unused if first)
    const float* __restrict__ bnaccPrev,  // prev layer bn3 stats (unused if first)
    const float* __restrict__ gPrev, const float* __restrict__ bPrev,
    float* __restrict__ hbuf, float* __restrict__ hsumL,
    const float* __restrict__ Whh, const float* __restrict__ bhh,
    const float* __restrict__ Wq,  const float* __restrict__ bq,
    float* __restrict__ gh, float* __restrict__ qkv, int first)
{
  __shared__ float sa[256];
  const int t = threadIdx.x, blk = blockIdx.x;
  const int r = t>>6, c = t&63;
  const int row0 = blk*4;
  const int row = row0 + r;

  float hv;
  if (first){
    hv = hbuf[row*64+c];
  } else {
    float mu = bnaccPrev[256+c]*(1.f/NB);
    float va = bnaccPrev[320+c]*(1.f/NB) - mu*mu;
    hv = gPrev[c]*(smlp[row*64+c]-mu)*rsqrtf(va+1e-5f)+bPrev[c];
    hbuf[row*64+c] = hv;
  }
  sa[t] = hv;
  __syncthreads();
  if (t<64){
    atomicAdd(&hsumL[t], sa[t]+sa[64+t]+sa[128+t]+sa[192+t]);
  }
  #pragma unroll
  for (int i=0;i<3;++i){
    int idx = t + 256*i;
    int rr = idx/192, cc = idx - rr*192;
    float ag = bhh[cc], aq = bq[cc];
    for (int k=0;k<64;++k){
      float hk = sa[rr*64+k];
      ag += hk*Whh[k*192+cc];
      aq += hk*Wq[k*192+cc];
    }
    gh[(row0+rr)*192+cc] = ag;
    qkv[(row0+rr)*192+cc] = aq;
  }
}

// ---------------- Kernel B (per layer): attention + o-proj + GRU + bn1/bn2 stats --------
__global__ __launch_bounds__(256) void k_B(
    const float* __restrict__ hbuf, const float* __restrict__ qkv,
    const float* __restrict__ gh,   const float* __restrict__ hsumL,
    const float* __restrict__ Wg,   const float* __restrict__ Wih,
    const float* __restrict__ bih,  const float* __restrict__ Wo,
    const float* __restrict__ bo,
    float* __restrict__ s1, float* __restrict__ s2, float* __restrict__ bnaccL)
{
  __shared__ float S[4*2048];
  __shared__ float sa[256];
  __shared__ float qs[256];
  __shared__ float os[256];
  __shared__ float smv_[64];
  __shared__ float sgi[192];
  __shared__ float lsum[4];
  const int t = threadIdx.x, blk = blockIdx.x;
  const int r = t>>6, c = t&63;
  const int row = blk*4 + r;

  if (t<64){
    float a=0.f;
    for (int k=0;k<64;++k) a += hsumL[k]*Wg[k*64+t];
    smv_[t]=a;
  }
  sa[t] = hbuf[row*64+c];
  qs[t] = qkv[row*192 + c];
  __syncthreads();
  if (t<192){
    float a = bih[t];
    for (int k=0;k<64;++k) a += smv_[k]*Wih[k*192+t];
    sgi[t]=a;
  }
  __syncthreads();

  for (int hd=0; hd<4; ++hd){
    // --- QK^T into LDS score panel ---
    float4 q0[4],q1[4],q2[4],q3[4];
    #pragma unroll
    for (int rr=0;rr<4;++rr){
      const float4* qp = (const float4*)&qs[rr*64 + hd*16];
      q0[rr]=qp[0]; q1[rr]=qp[1]; q2[rr]=qp[2]; q3[rr]=qp[3];
    }
    #pragma unroll 2
    for (int j=0;j<8;++j){
      int key = t + 256*j;
      const float4* kp = (const float4*)&qkv[(size_t)key*192 + 64 + hd*16];
      float4 k0=kp[0], k1=kp[1], k2=kp[2], k3=kp[3];
      #pragma unroll
      for (int rr=0;rr<4;++rr){
        float sd = k0.x*q0[rr].x + k0.y*q0[rr].y + k0.z*q0[rr].z + k0.w*q0[rr].w
                 + k1.x*q1[rr].x + k1.y*q1[rr].y + k1.z*q1[rr].z + k1.w*q1[rr].w
                 + k2.x*q2[rr].x + k2.y*q2[rr].y + k2.z*q2[rr].z + k2.w*q2[rr].w
                 + k3.x*q3[rr].x + k3.y*q3[rr].y + k3.z*q3[rr].z + k3.w*q3[rr].w;
        S[rr*2048+key] = 0.25f*sd;
      }
    }
    __syncthreads();
    // --- softmax: wave r owns row r ---
    {
      float mx = -1e30f;
      for (int j=0;j<32;++j) mx = fmaxf(mx, S[r*2048 + c + 64*j]);
      #pragma unroll
      for (int off=32; off>0; off>>=1) mx = fmaxf(mx, __shfl_xor(mx, off, 64));
      float sum=0.f;
      for (int j=0;j<32;++j){
        int idx = r*2048 + c + 64*j;
        float e = __expf(S[idx]-mx);
        S[idx]=e; sum+=e;
      }
      #pragma unroll
      for (int off=32; off>0; off>>=1) sum += __shfl_xor(sum, off, 64);
      if (c==0) lsum[r]=sum;
    }
    __syncthreads();
    // --- AV ---
    {
      const int dq = t&3, ks = (t>>2)&15;
      float4 acc; acc.x=0.f; acc.y=0.f; acc.z=0.f; acc.w=0.f;
      for (int j=0;j<128;++j){
        int key = ks + 16*j;
        float pw = S[r*2048+key];
        const float4 v = *(const float4*)&qkv[(size_t)key*192 + 128 + hd*16 + 4*dq];
        acc.x += pw*v.x; acc.y += pw*v.y; acc.z += pw*v.z; acc.w += pw*v.w;
      }
      #pragma unroll
      for (int off=4; off<64; off<<=1){
        acc.x += __shfl_xor(acc.x, off, 64);
        acc.y += __shfl_xor(acc.y, off, 64);
        acc.z += __shfl_xor(acc.z, off, 64);
        acc.w += __shfl_xor(acc.w, off, 64);
      }
      if (ks==0){
        float inv = 1.f/lsum[r];
        float* op = &os[r*64 + hd*16 + 4*dq];
        op[0]=acc.x*inv; op[1]=acc.y*inv; op[2]=acc.z*inv; op[3]=acc.w*inv;
      }
    }
    __syncthreads();
  }

  // --- o-proj + residual (s2), GRU + residual (s1), bn1/bn2 stats ---
  float o2 = bo[c];
  for (int k=0;k<64;++k) o2 += os[r*64+k]*Wo[k*64+c];
  float hv = sa[t];
  float s2v = o2 + hv;
  float ir = sgi[c]      + gh[row*192+c];
  float iz = sgi[64+c]   + gh[row*192+64+c];
  float inn = sgi[128+c];
  float hn  = gh[row*192+128+c];
  float rr_ = sigmoidf_(ir);
  float zz  = sigmoidf_(iz);
  float nn  = tanhfast_(inn + rr_*hn);
  float s1v = (1.f-zz)*nn + zz*hv + hv;    // hc + h
  s1[row*64+c] = s1v;
  s2[row*64+c] = s2v;
  S[t] = s1v; S[256+t] = s2v;
  __syncthreads();
  if (t<64){
    float a=0.f,aq=0.f,b=0.f,bq2=0.f;
    #pragma unroll
    for (int rr=0;rr<4;++rr){
      float v1 = S[rr*64+t], v2 = S[256+rr*64+t];
      a+=v1; aq+=v1*v1; b+=v2; bq2+=v2*v2;
    }
    atomicAdd(&bnaccL[t],a);     atomicAdd(&bnaccL[64+t],aq);
    atomicAdd(&bnaccL[128+t],b); atomicAdd(&bnaccL[192+t],bq2);
  }
}

// ---------------- Kernel C (per layer): bn1/bn2 apply + MLP + bn3 stats ----------------
__global__ __launch_bounds__(256) void k_C(
    const float* __restrict__ s1, const float* __restrict__ s2,
    const float* __restrict__ bngL, const float* __restrict__ bnbL, // bn1 at +0, bn2 at +64
    const float* __restrict__ W1, const float* __restrict__ b1,
    const float* __restrict__ W2, const float* __restrict__ b2,
    float* __restrict__ smlp, float* __restrict__ bnaccL)
{
  __shared__ float sa[256];
  __shared__ float sh[512];
  __shared__ float S2[256];
  const int t = threadIdx.x, blk = blockIdx.x;
  const int r = t>>6, c = t&63;
  const int row = blk*4 + r;

  float mu1 = bnaccL[c]*(1.f/NB);
  float va1 = bnaccL[64+c]*(1.f/NB) - mu1*mu1;
  float mu2 = bnaccL[128+c]*(1.f/NB);
  float va2 = bnaccL[192+c]*(1.f/NB) - mu2*mu2;
  float h1 = bngL[c]*(s1[row*64+c]-mu1)*rsqrtf(va1+1e-5f)+bnbL[c];
  float h2 = bngL[64+c]*(s2[row*64+c]-mu2)*rsqrtf(va2+1e-5f)+bnbL[64+c];
  float sv = h1+h2;
  sa[t]=sv;
  __syncthreads();
  #pragma unroll
  for (int i=0;i<2;++i){
    int idx = t + 256*i;
    int rr = idx>>7, hj = idx&127;
    float a = b1[hj];
    for (int k=0;k<64;++k) a += sa[rr*64+k]*W1[k*128+hj];
    sh[idx] = fmaxf(a, 0.f);
  }
  __syncthreads();
  float mo = b2[c];
  for (int k=0;k<128;++k) mo += sh[r*128+k]*W2[k*64+c];
  float smv2 = sv + mo;
  smlp[row*64+c]=smv2;
  S2[t]=smv2;
  __syncthreads();
  if (t<64){
    float a=0.f,aq=0.f;
    #pragma unroll
    for (int rr=0;rr<4;++rr){ float v=S2[rr*64+t]; a+=v; aq+=v*v; }
    atomicAdd(&bnaccL[256+t],a); atomicAdd(&bnaccL[320+t],aq);
  }
}

// ---------------- Kernel: GEMM2 with fused final bn3 ----------------
__global__ __launch_bounds__(256) void k_out(
  const float* __restrict__ smlp, const float* __restrict__ bnacc4,
  const float* __restrict__ g4, const float* __restrict__ b4,
  const float* __restrict__ outW, const float* __restrict__ outb,
  float* __restrict__ out)
{
  __shared__ float hsT[64*20];
  const int t = threadIdx.x, blk = blockIdx.x;
  const int rg = blk>>2, cg = blk&3;
  const int rows0 = rg*16;
  #pragma unroll
  for (int i=0;i<4;++i){
    int idx = t + 256*i;
    int k = idx&63, rr = idx>>6;
    float mu = bnacc4[256+k]*(1.f/NB);
    float va = bnacc4[320+k]*(1.f/NB)-mu*mu;
    hsT[k*20+rr] = g4[k]*(smlp[(size_t)(rows0+rr)*64+k]-mu)*rsqrtf(va+1e-5f)+b4[k];
  }
  __syncthreads();
  for (int j=0;j<4;++j){
    int cc = cg*1024 + t + 256*j;
    float acc[16];
    float bv = outb[cc];
    #pragma unroll
    for (int rr=0;rr<16;++rr) acc[rr]=bv;
    for (int k=0;k<64;++k){
      float w = outW[(size_t)k*4096+cc];
      const float4* hp = (const float4*)&hsT[k*20];
      float4 h0=hp[0], h1=hp[1], h2=hp[2], h3=hp[3];
      acc[0]+=h0.x*w;  acc[1]+=h0.y*w;  acc[2]+=h0.z*w;  acc[3]+=h0.w*w;
      acc[4]+=h1.x*w;  acc[5]+=h1.y*w;  acc[6]+=h1.z*w;  acc[7]+=h1.w*w;
      acc[8]+=h2.x*w;  acc[9]+=h2.y*w;  acc[10]+=h2.z*w; acc[11]+=h2.w*w;
      acc[12]+=h3.x*w; acc[13]+=h3.y*w; acc[14]+=h3.z*w; acc[15]+=h3.w*w;
    }
    #pragma unroll
    for (int rr=0;rr<16;++rr) out[(size_t)(rows0+rr)*4096+cc]=acc[rr];
  }
}

extern "C" void kernel_launch(void* const* d_in, const int* in_sizes, int n_in,
                              void* d_out, int out_size, void* d_ws, size_t ws_size,
                              hipStream_t stream)
{
  (void)in_sizes; (void)n_in; (void)out_size; (void)ws_size;
  const float* x      = (const float*)d_in[0];
  const float* tt     = (const float*)d_in[1];
  const float* freqs  = (const float*)d_in[2];
  const float* fc1W   = (const float*)d_in[3];
  const float* fc1b   = (const float*)d_in[4];
  const float* fc2W   = (const float*)d_in[5];
  const float* fc2b   = (const float*)d_in[6];
  const float* nodeW  = (const float*)d_in[7];
  const float* nodeb  = (const float*)d_in[8];
  const float* tprojW = (const float*)d_in[9];
  const float* tprojb = (const float*)d_in[10];
  const float* tcatW  = (const float*)d_in[11];
  const float* tcatb  = (const float*)d_in[12];
  const float* penb   = (const float*)d_in[14];
  const float* pelW   = (const float*)d_in[15];
  const float* pelb   = (const float*)d_in[16];
  const float* catW   = (const float*)d_in[17];
  const float* catb   = (const float*)d_in[18];
  const float* convWg = (const float*)d_in[19];
  const float* gruWih = (const float*)d_in[20];
  const float* grubih = (const float*)d_in[21];
  const float* gruWhh = (const float*)d_in[22];
  const float* grubhh = (const float*)d_in[23];
  const float* Wqkv   = (const float*)d_in[24];
  const float* bqkv   = (const float*)d_in[25];
  const float* Wo     = (const float*)d_in[26];
  const float* bo     = (const float*)d_in[27];
  const float* bng    = (const float*)d_in[28];
  const float* bnb    = (const float*)d_in[29];
  const float* W1     = (const float*)d_in[30];
  const float* b1     = (const float*)d_in[31];
  const float* W2     = (const float*)d_in[32];
  const float* b2     = (const float*)d_in[33];
  const float* outW   = (const float*)d_in[34];
  const float* outb   = (const float*)d_in[35];

  float* ws = (float*)d_ws;
  float* h0p   = ws;                  // 524288
  float* htime = h0p + 524288;        // 131072
  float* hbuf  = htime + 131072;      // 131072
  float* gh    = hbuf + 131072;       // 393216
  float* qkv   = gh + 393216;         // 393216
  float* s1    = qkv + 393216;        // 131072
  float* s2    = s1 + 131072;         // 131072
  float* smlp  = s2 + 131072;         // 131072
  float* hsum  = smlp + 131072;       // 320  (5 layers x 64) -- contiguous with bnacc
  float* bnacc = hsum + 320;          // 1920 (5 layers x 384)

  dim3 G(512), Blk(256);

  k_pre<<<G, Blk, 0, stream>>>(x, tt, freqs, fc1W, fc1b, fc2W, fc2b,
                               tprojW, tprojb, nodeW, h0p, htime, hsum);

  k_assemble<<<G, Blk, 0, stream>>>(h0p, htime, nodeb, tcatW, tcatb,
                                    penb, pelW, pelb, catW, catb, hbuf);

  for (int l=0; l<NLAY; ++l){
    const float* bnaccPrev = (l==0) ? bnacc : bnacc + (l-1)*384;
    const float* gPrev = (l==0) ? bng : bng + (l-1)*192 + 128;
    const float* bPrev = (l==0) ? bnb : bnb + (l-1)*192 + 128;
    k_A<<<G, Blk, 0, stream>>>(smlp, bnaccPrev, gPrev, bPrev,
                               hbuf, hsum + l*64,
                               gruWhh + l*12288, grubhh + l*192,
                               Wqkv + l*12288, bqkv + l*192,
                               gh, qkv, (l==0) ? 1 : 0);
    k_B<<<G, Blk, 0, stream>>>(hbuf, qkv, gh, hsum + l*64,
                               convWg + l*4096, gruWih + l*12288, grubih + l*192,
                               Wo + l*4096, bo + l*64,
                               s1, s2, bnacc + l*384);
    k_C<<<G, Blk, 0, stream>>>(s1, s2, bng + l*192, bnb + l*192,
                               W1 + l*8192, b1 + l*128, W2 + l*8192, b2 + l*64,
                               smlp, bnacc + l*384);
  }

  k_out<<<G, Blk, 0, stream>>>(smlp, bnacc + 4*384, bng + 896, bnb + 896,
                               outW, outb, (float*)d_out);
}

// Round 3
// 638.510 us; speedup vs baseline: 1.8480x; 1.8480x over previous
//
#include <hip/hip_runtime.h>

#define NB 2048
#define HDM 64
#define NLAY 5

typedef __bf16 bf16x8 __attribute__((ext_vector_type(8)));
typedef float v4f __attribute__((ext_vector_type(4)));

__device__ __forceinline__ float sigmoidf_(float x){ return 1.f/(1.f+__expf(-x)); }
__device__ __forceinline__ float tanhfast_(float x){
  x = fminf(fmaxf(x, -15.f), 15.f);
  float e = __expf(2.f*x);
  return (e-1.f)/(e+1.f);
}
__device__ __forceinline__ unsigned short f2b_rne(float f){
  unsigned u = __float_as_uint(f);
  unsigned r = u + 0x7FFFu + ((u>>16)&1u);
  return (unsigned short)(r>>16);
}
// pack two floats to bf16x2 dword (round-to-nearest-ish)
__device__ __forceinline__ unsigned pk2(float a, float b){
  unsigned ua = (__float_as_uint(a) + 0x8000u) >> 16;
  unsigned ub = (__float_as_uint(b) + 0x8000u) & 0xFFFF0000u;
  return ua | ub;
}

// ---------------- Kernel: time-embedding + GEMM1 K-split partials + zero accumulators ---------
__global__ __launch_bounds__(256) void k_pre(
    const float* __restrict__ x, const float* __restrict__ tt,
    const float* __restrict__ freqs,
    const float* __restrict__ fc1W, const float* __restrict__ fc1b,
    const float* __restrict__ fc2W, const float* __restrict__ fc2b,
    const float* __restrict__ tprojW, const float* __restrict__ tprojb,
    const float* __restrict__ nodeW,
    float* __restrict__ h0p, float* __restrict__ htime,
    float* __restrict__ zero_region)   // hsum(320) + bnacc(1920) contiguous
{
  __shared__ float xs[16*256];
  __shared__ float tb0[256];
  __shared__ float tb1[256];
  const int t = threadIdx.x, blk = blockIdx.x;
  const int r = t>>6, c = t&63;

  if (blk == 0){
    for (int i = t; i < 320 + 1920; i += 256) zero_region[i] = 0.f;
  }

  {
    const int row = blk*4 + r;
    const float tv = tt[row];
    float te[16];
    #pragma unroll
    for (int j=0;j<8;++j){
      float sv, cv;
      __sincosf(6.28318530717958647692f*tv*freqs[j], &sv, &cv);
      te[j]=sv; te[j+8]=cv;
    }
    float a = fc1b[c];
    #pragma unroll
    for (int j=0;j<16;++j) a += te[j]*fc1W[j*64+c];
    tb0[t] = a*sigmoidf_(a);
    __syncthreads();
    float b2 = fc2b[c];
    for (int k=0;k<64;++k) b2 += tb0[r*64+k]*fc2W[k*64+c];
    tb1[t] = b2;
    __syncthreads();
    float hti = tprojb[c];
    for (int k=0;k<64;++k) hti += tb1[r*64+k]*tprojW[k*64+c];
    htime[row*64+c] = hti;
  }

  const int rg = blk>>2, kq = blk&3;
  const int rows0 = rg*16, k0 = kq*1024;
  const int cq = t&15, rr = t>>4;
  float4 acc; acc.x=0.f; acc.y=0.f; acc.z=0.f; acc.w=0.f;
  for (int ch=0; ch<4; ++ch){
    __syncthreads();
    const int kb = k0 + ch*256;
    #pragma unroll
    for (int i=0;i<4;++i){
      int fi = t + 256*i;
      int xr = fi>>6, kk = (fi&63)<<2;
      *(float4*)&xs[xr*256+kk] = *(const float4*)&x[(size_t)(rows0+xr)*4096 + kb + kk];
    }
    __syncthreads();
    #pragma unroll 4
    for (int k=0;k<256;++k){
      float4 w = *(const float4*)&nodeW[(size_t)(kb+k)*64 + 4*cq];
      float xv = xs[rr*256+k];
      acc.x += xv*w.x; acc.y += xv*w.y; acc.z += xv*w.z; acc.w += xv*w.w;
    }
  }
  *(float4*)&h0p[(size_t)kq*(NB*HDM) + (rows0+rr)*64 + 4*cq] = acc;
}

// ---------------- Kernel: assemble h ----------------
__global__ __launch_bounds__(256) void k_assemble(
    const float* __restrict__ h0p, const float* __restrict__ htime,
    const float* __restrict__ nodeb,
    const float* __restrict__ tcatW, const float* __restrict__ tcatb,
    const float* __restrict__ penb, const float* __restrict__ pelW,
    const float* __restrict__ pelb,
    const float* __restrict__ catW, const float* __restrict__ catb,
    float* __restrict__ hbuf)
{
  __shared__ float sa[256];
  __shared__ float sb[256];
  __shared__ float cvec[64];
  const int t = threadIdx.x, blk = blockIdx.x;
  const int r = t>>6, c = t&63;
  const int row = blk*4 + r;

  if (r==0){
    float pl[16];
    #pragma unroll
    for (int j=0;j<16;++j){
      float a = pelb[j];
      for (int w=0;w<20;++w) a += penb[w]*pelW[w*16+j];
      pl[j]=a;
    }
    float a = catb[c];
    #pragma unroll
    for (int j=0;j<16;++j) a += pl[j]*catW[(64+j)*64+c];
    cvec[c]=a;
  }
  float h0 = nodeb[c];
  #pragma unroll
  for (int q=0;q<4;++q) h0 += h0p[(size_t)q*(NB*HDM) + row*64 + c];
  sa[t] = h0;
  sb[t] = htime[row*64+c];
  __syncthreads();
  float a = tcatb[c];
  for (int k=0;k<64;++k) a += sa[r*64+k]*tcatW[k*64+c];
  for (int k=0;k<64;++k) a += sb[r*64+k]*tcatW[(64+k)*64+c];
  __syncthreads();
  sa[t] = a;
  __syncthreads();
  float hv = cvec[c];
  for (int k=0;k<64;++k) hv += sa[r*64+k]*catW[k*64+c];
  hbuf[row*64+c] = hv;
}

// ---------------- Kernel A (per layer): [bn3 of prev] + hsum + gh + bf16 QKV packs ----------
__global__ __launch_bounds__(256) void k_A(
    const float* __restrict__ smlp,
    const float* __restrict__ bnaccPrev,
    const float* __restrict__ gPrev, const float* __restrict__ bPrev,
    float* __restrict__ hbuf, float* __restrict__ hsumL,
    const float* __restrict__ Whh, const float* __restrict__ bhh,
    const float* __restrict__ Wq,  const float* __restrict__ bq,
    float* __restrict__ gh,
    unsigned short* __restrict__ Qb, unsigned short* __restrict__ Kb,
    unsigned short* __restrict__ Vt, int first)
{
  __shared__ float sa[256];
  const int t = threadIdx.x, blk = blockIdx.x;
  const int r = t>>6, c = t&63;
  const int row0 = blk*4;
  const int row = row0 + r;

  float hv;
  if (first){
    hv = hbuf[row*64+c];
  } else {
    float mu = bnaccPrev[256+c]*(1.f/NB);
    float va = bnaccPrev[320+c]*(1.f/NB) - mu*mu;
    hv = gPrev[c]*(smlp[row*64+c]-mu)*rsqrtf(va+1e-5f)+bPrev[c];
    hbuf[row*64+c] = hv;
  }
  sa[t] = hv;
  __syncthreads();
  if (t<64){
    atomicAdd(&hsumL[t], sa[t]+sa[64+t]+sa[128+t]+sa[192+t]);
  }
  #pragma unroll
  for (int i=0;i<3;++i){
    int idx = t + 256*i;
    int rr = idx/192, cc = idx - rr*192;
    float ag = bhh[cc], aq = bq[cc];
    for (int k=0;k<64;++k){
      float hk = sa[rr*64+k];
      ag += hk*Whh[k*192+cc];
      aq += hk*Wq[k*192+cc];
    }
    int rw = row0+rr;
    gh[(size_t)rw*192+cc] = ag;
    if (cc < 64){
      int hd = cc>>4, dh = cc&15;
      size_t base = ((size_t)(hd<<11) + rw)*32;
      Qb[base+dh] = f2b_rne(aq*0.25f);   // fold 1/sqrt(16)
      Qb[base+16+dh] = 0;
    } else if (cc < 128){
      int c2 = cc-64, hd = c2>>4, dh = c2&15;
      size_t base = ((size_t)(hd<<11) + rw)*32;
      Kb[base+dh] = f2b_rne(aq);
      Kb[base+16+dh] = 0;
    } else {
      int c2 = cc-128, hd = c2>>4, dh = c2&15;
      Vt[((size_t)(hd*16+dh))*2048 + rw] = f2b_rne(aq);
    }
  }
}

// ---------------- Kernel: flash attention, MFMA, K-split in 4 parts ----------------
// grid 2048 x 64. job: qt = b&127, head = (b>>7)&3, part = b>>9. 512 keys per part.
__global__ __launch_bounds__(64) void k_attn(
    const unsigned short* __restrict__ Qb, const unsigned short* __restrict__ Kb,
    const unsigned short* __restrict__ Vt,
    float* __restrict__ Upart, float* __restrict__ mpart, float* __restrict__ lpart)
{
  __shared__ unsigned short Pl[16*40];   // padded rows: 40 bf16 (80B) to dodge bank conflicts
  const int lane = threadIdx.x;
  const int q15 = lane & 15, quad = lane >> 4;
  const int b = blockIdx.x;
  const int qt = b & 127, head = (b>>7)&3, part = b>>9;
  const int qrow = qt*16 + q15;
  const int key00 = part*512;

  const bf16x8 qf = *(const bf16x8*)&Qb[(((size_t)(head<<11))+qrow)*32 + quad*8];
  const unsigned short* Kb_h = Kb + ((size_t)(head<<11))*32;
  const unsigned short* Vrow = Vt + ((size_t)(head*16+q15))*2048;

  v4f O = {0.f,0.f,0.f,0.f};
  float m = -1e30f, lsum = 0.f;

  bf16x8 kf0 = *(const bf16x8*)&Kb_h[(size_t)(key00 + q15)*32 + quad*8];
  bf16x8 kf1 = *(const bf16x8*)&Kb_h[(size_t)(key00 + 16 + q15)*32 + quad*8];
  bf16x8 vf  = *(const bf16x8*)&Vrow[key00 + quad*8];

  for (int c=0; c<16; ++c){
    bf16x8 nk0, nk1, nv;
    if (c < 15){
      int nk = key00 + (c+1)*32;
      nk0 = *(const bf16x8*)&Kb_h[(size_t)(nk + q15)*32 + quad*8];
      nk1 = *(const bf16x8*)&Kb_h[(size_t)(nk + 16 + q15)*32 + quad*8];
      nv  = *(const bf16x8*)&Vrow[nk + quad*8];
    }
    v4f z = {0.f,0.f,0.f,0.f};
    // S^T[key][q] = K[key][dh] . Q^T[dh][q]   (dh padded to 32 with zeros)
    v4f s0 = __builtin_amdgcn_mfma_f32_16x16x32_bf16(kf0, qf, z, 0,0,0);
    v4f s1 = __builtin_amdgcn_mfma_f32_16x16x32_bf16(kf1, qf, z, 0,0,0);
    // online softmax per q-column (lane&15); cross-quad reduce via shfl
    float cmax = fmaxf(fmaxf(fmaxf(s0[0],s0[1]),fmaxf(s0[2],s0[3])),
                       fmaxf(fmaxf(s1[0],s1[1]),fmaxf(s1[2],s1[3])));
    cmax = fmaxf(cmax, __shfl_xor(cmax,16,64));
    cmax = fmaxf(cmax, __shfl_xor(cmax,32,64));
    float mnew = fmaxf(m, cmax);
    float alpha = __expf(m - mnew);
    float p0=__expf(s0[0]-mnew), p1=__expf(s0[1]-mnew), p2=__expf(s0[2]-mnew), p3=__expf(s0[3]-mnew);
    float p4=__expf(s1[0]-mnew), p5=__expf(s1[1]-mnew), p6=__expf(s1[2]-mnew), p7=__expf(s1[3]-mnew);
    lsum = alpha*lsum + ((p0+p1)+(p2+p3)+((p4+p5)+(p6+p7)));   // per-quad partial
    m = mnew;
    O[0]*=alpha; O[1]*=alpha; O[2]*=alpha; O[3]*=alpha;
    // P^T -> LDS (C-layout regs are keys quad*4+r), re-read as B-fragment
    *(uint2*)&Pl[q15*40 + quad*4]      = make_uint2(pk2(p0,p1), pk2(p2,p3));
    *(uint2*)&Pl[q15*40 + 16 + quad*4] = make_uint2(pk2(p4,p5), pk2(p6,p7));
    __syncthreads();
    bf16x8 pf = *(const bf16x8*)&Pl[q15*40 + quad*8];
    // O^T[dh][q] += V^T[dh][key] . P^T[key][q]   (K-dim = 32 keys)
    O = __builtin_amdgcn_mfma_f32_16x16x32_bf16(vf, pf, O, 0,0,0);
    kf0 = nk0; kf1 = nk1; vf = nv;
  }
  lsum += __shfl_xor(lsum,16,64);
  lsum += __shfl_xor(lsum,32,64);
  size_t ub = ((size_t)((part*4+head)*2048) + qrow)*16 + quad*4;
  *(float4*)&Upart[ub] = make_float4(O[0],O[1],O[2],O[3]);
  if (quad==0){
    mpart[(size_t)(part*4+head)*2048 + qrow] = m;
    lpart[(size_t)(part*4+head)*2048 + qrow] = lsum;
  }
}

// ---------------- Kernel B2 (per layer): combine partials + o-proj + GRU + bn1/bn2 stats ----
__global__ __launch_bounds__(256) void k_B2(
    const float* __restrict__ hbuf, const float* __restrict__ gh,
    const float* __restrict__ hsumL,
    const float* __restrict__ Upart, const float* __restrict__ mpart,
    const float* __restrict__ lpart,
    const float* __restrict__ Wg,   const float* __restrict__ Wih,
    const float* __restrict__ bih,  const float* __restrict__ Wo,
    const float* __restrict__ bo,
    float* __restrict__ s1, float* __restrict__ s2, float* __restrict__ bnaccL)
{
  __shared__ float sa[256];
  __shared__ float os[256];
  __shared__ float smv_[64];
  __shared__ float sgi[192];
  __shared__ float Sb[512];
  const int t = threadIdx.x, blk = blockIdx.x;
  const int r = t>>6, c = t&63;
  const int row = blk*4 + r;
  const int head = c>>4, dh = c&15;

  if (t<64){
    float a=0.f;
    for (int k=0;k<64;++k) a += hsumL[k]*Wg[k*64+t];
    smv_[t]=a;
  }
  sa[t] = hbuf[row*64+c];

  // merge 4 K-split partials
  float m0 = mpart[(size_t)(head)*2048+row],    m1 = mpart[(size_t)(4+head)*2048+row];
  float m2 = mpart[(size_t)(8+head)*2048+row],  m3 = mpart[(size_t)(12+head)*2048+row];
  float mm = fmaxf(fmaxf(m0,m1),fmaxf(m2,m3));
  float a0=__expf(m0-mm), a1=__expf(m1-mm), a2=__expf(m2-mm), a3=__expf(m3-mm);
  float ll = a0*lpart[(size_t)(head)*2048+row]   + a1*lpart[(size_t)(4+head)*2048+row]
           + a2*lpart[(size_t)(8+head)*2048+row] + a3*lpart[(size_t)(12+head)*2048+row];
  float uu = a0*Upart[((size_t)(head)*2048+row)*16+dh]    + a1*Upart[((size_t)(4+head)*2048+row)*16+dh]
           + a2*Upart[((size_t)(8+head)*2048+row)*16+dh]  + a3*Upart[((size_t)(12+head)*2048+row)*16+dh];
  os[t] = uu / ll;
  __syncthreads();
  if (t<192){
    float a = bih[t];
    for (int k=0;k<64;++k) a += smv_[k]*Wih[k*192+t];
    sgi[t]=a;
  }
  __syncthreads();

  float o2 = bo[c];
  for (int k=0;k<64;++k) o2 += os[r*64+k]*Wo[k*64+c];
  float hv = sa[t];
  float s2v = o2 + hv;
  float ir = sgi[c]      + gh[(size_t)row*192+c];
  float iz = sgi[64+c]   + gh[(size_t)row*192+64+c];
  float inn = sgi[128+c];
  float hn  = gh[(size_t)row*192+128+c];
  float rr_ = sigmoidf_(ir);
  float zz  = sigmoidf_(iz);
  float nn  = tanhfast_(inn + rr_*hn);
  float s1v = (1.f-zz)*nn + zz*hv + hv;    // hc + h
  s1[row*64+c] = s1v;
  s2[row*64+c] = s2v;
  Sb[t] = s1v; Sb[256+t] = s2v;
  __syncthreads();
  if (t<64){
    float a=0.f,aq=0.f,b=0.f,bq2=0.f;
    #pragma unroll
    for (int rr=0;rr<4;++rr){
      float v1 = Sb[rr*64+t], v2 = Sb[256+rr*64+t];
      a+=v1; aq+=v1*v1; b+=v2; bq2+=v2*v2;
    }
    atomicAdd(&bnaccL[t],a);     atomicAdd(&bnaccL[64+t],aq);
    atomicAdd(&bnaccL[128+t],b); atomicAdd(&bnaccL[192+t],bq2);
  }
}

// ---------------- Kernel C (per layer): bn1/bn2 apply + MLP + bn3 stats ----------------
__global__ __launch_bounds__(256) void k_C(
    const float* __restrict__ s1, const float* __restrict__ s2,
    const float* __restrict__ bngL, const float* __restrict__ bnbL,
    const float* __restrict__ W1, const float* __restrict__ b1,
    const float* __restrict__ W2, const float* __restrict__ b2,
    float* __restrict__ smlp, float* __restrict__ bnaccL)
{
  __shared__ float sa[256];
  __shared__ float sh[512];
  __shared__ float S2[256];
  const int t = threadIdx.x, blk = blockIdx.x;
  const int r = t>>6, c = t&63;
  const int row = blk*4 + r;

  float mu1 = bnaccL[c]*(1.f/NB);
  float va1 = bnaccL[64+c]*(1.f/NB) - mu1*mu1;
  float mu2 = bnaccL[128+c]*(1.f/NB);
  float va2 = bnaccL[192+c]*(1.f/NB) - mu2*mu2;
  float h1 = bngL[c]*(s1[row*64+c]-mu1)*rsqrtf(va1+1e-5f)+bnbL[c];
  float h2 = bngL[64+c]*(s2[row*64+c]-mu2)*rsqrtf(va2+1e-5f)+bnbL[64+c];
  float sv = h1+h2;
  sa[t]=sv;
  __syncthreads();
  #pragma unroll
  for (int i=0;i<2;++i){
    int idx = t + 256*i;
    int rr = idx>>7, hj = idx&127;
    float a = b1[hj];
    for (int k=0;k<64;++k) a += sa[rr*64+k]*W1[k*128+hj];
    sh[idx] = fmaxf(a, 0.f);
  }
  __syncthreads();
  float mo = b2[c];
  for (int k=0;k<128;++k) mo += sh[r*128+k]*W2[k*64+c];
  float smv2 = sv + mo;
  smlp[row*64+c]=smv2;
  S2[t]=smv2;
  __syncthreads();
  if (t<64){
    float a=0.f,aq=0.f;
    #pragma unroll
    for (int rr=0;rr<4;++rr){ float v=S2[rr*64+t]; a+=v; aq+=v*v; }
    atomicAdd(&bnaccL[256+t],a); atomicAdd(&bnaccL[320+t],aq);
  }
}

// ---------------- Kernel: GEMM2 with fused final bn3 ----------------
__global__ __launch_bounds__(256) void k_out(
  const float* __restrict__ smlp, const float* __restrict__ bnacc4,
  const float* __restrict__ g4, const float* __restrict__ b4,
  const float* __restrict__ outW, const float* __restrict__ outb,
  float* __restrict__ out)
{
  __shared__ float hsT[64*20];
  const int t = threadIdx.x, blk = blockIdx.x;
  const int rg = blk>>2, cg = blk&3;
  const int rows0 = rg*16;
  #pragma unroll
  for (int i=0;i<4;++i){
    int idx = t + 256*i;
    int k = idx&63, rr = idx>>6;
    float mu = bnacc4[256+k]*(1.f/NB);
    float va = bnacc4[320+k]*(1.f/NB)-mu*mu;
    hsT[k*20+rr] = g4[k]*(smlp[(size_t)(rows0+rr)*64+k]-mu)*rsqrtf(va+1e-5f)+b4[k];
  }
  __syncthreads();
  for (int j=0;j<4;++j){
    int cc = cg*1024 + t + 256*j;
    float acc[16];
    float bv = outb[cc];
    #pragma unroll
    for (int rr=0;rr<16;++rr) acc[rr]=bv;
    for (int k=0;k<64;++k){
      float w = outW[(size_t)k*4096+cc];
      const float4* hp = (const float4*)&hsT[k*20];
      float4 h0=hp[0], h1=hp[1], h2=hp[2], h3=hp[3];
      acc[0]+=h0.x*w;  acc[1]+=h0.y*w;  acc[2]+=h0.z*w;  acc[3]+=h0.w*w;
      acc[4]+=h1.x*w;  acc[5]+=h1.y*w;  acc[6]+=h1.z*w;  acc[7]+=h1.w*w;
      acc[8]+=h2.x*w;  acc[9]+=h2.y*w;  acc[10]+=h2.z*w; acc[11]+=h2.w*w;
      acc[12]+=h3.x*w; acc[13]+=h3.y*w; acc[14]+=h3.z*w; acc[15]+=h3.w*w;
    }
    #pragma unroll
    for (int rr=0;rr<16;++rr) out[(size_t)(rows0+rr)*4096+cc]=acc[rr];
  }
}

extern "C" void kernel_launch(void* const* d_in, const int* in_sizes, int n_in,
                              void* d_out, int out_size, void* d_ws, size_t ws_size,
                              hipStream_t stream)
{
  (void)in_sizes; (void)n_in; (void)out_size; (void)ws_size;
  const float* x      = (const float*)d_in[0];
  const float* tt     = (const float*)d_in[1];
  const float* freqs  = (const float*)d_in[2];
  const float* fc1W   = (const float*)d_in[3];
  const float* fc1b   = (const float*)d_in[4];
  const float* fc2W   = (const float*)d_in[5];
  const float* fc2b   = (const float*)d_in[6];
  const float* nodeW  = (const float*)d_in[7];
  const float* nodeb  = (const float*)d_in[8];
  const float* tprojW = (const float*)d_in[9];
  const float* tprojb = (const float*)d_in[10];
  const float* tcatW  = (const float*)d_in[11];
  const float* tcatb  = (const float*)d_in[12];
  const float* penb   = (const float*)d_in[14];
  const float* pelW   = (const float*)d_in[15];
  const float* pelb   = (const float*)d_in[16];
  const float* catW   = (const float*)d_in[17];
  const float* catb   = (const float*)d_in[18];
  const float* convWg = (const float*)d_in[19];
  const float* gruWih = (const float*)d_in[20];
  const float* grubih = (const float*)d_in[21];
  const float* gruWhh = (const float*)d_in[22];
  const float* grubhh = (const float*)d_in[23];
  const float* Wqkv   = (const float*)d_in[24];
  const float* bqkv   = (const float*)d_in[25];
  const float* Wo     = (const float*)d_in[26];
  const float* bo     = (const float*)d_in[27];
  const float* bng    = (const float*)d_in[28];
  const float* bnb    = (const float*)d_in[29];
  const float* W1     = (const float*)d_in[30];
  const float* b1     = (const float*)d_in[31];
  const float* W2     = (const float*)d_in[32];
  const float* b2     = (const float*)d_in[33];
  const float* outW   = (const float*)d_in[34];
  const float* outb   = (const float*)d_in[35];

  float* ws = (float*)d_ws;
  float* h0p   = ws;                  // 524288
  float* htime = h0p + 524288;        // 131072
  float* hbuf  = htime + 131072;      // 131072
  float* gh    = hbuf + 131072;       // 393216
  float* s1    = gh + 393216;         // 131072
  float* s2    = s1 + 131072;         // 131072
  float* smlp  = s2 + 131072;         // 131072
  float* Upart = smlp + 131072;       // 524288 (4 parts x 4 heads x 2048 x 16)
  float* mpart = Upart + 524288;      // 32768
  float* lpart = mpart + 32768;       // 32768
  float* hsum  = lpart + 32768;       // 320  (contiguous with bnacc for zeroing)
  float* bnacc = hsum + 320;          // 1920
  unsigned short* Qb = (unsigned short*)(bnacc + 1920);  // 4*2048*32 bf16 = 131072 fl
  unsigned short* Kb = Qb + 262144;                      // 131072 fl
  unsigned short* Vt = Kb + 262144;                      // 4*16*2048 bf16 = 65536 fl

  dim3 G(512), Blk(256);

  k_pre<<<G, Blk, 0, stream>>>(x, tt, freqs, fc1W, fc1b, fc2W, fc2b,
                               tprojW, tprojb, nodeW, h0p, htime, hsum);

  k_assemble<<<G, Blk, 0, stream>>>(h0p, htime, nodeb, tcatW, tcatb,
                                    penb, pelW, pelb, catW, catb, hbuf);

  for (int l=0; l<NLAY; ++l){
    const float* bnaccPrev = (l==0) ? bnacc : bnacc + (l-1)*384;
    const float* gPrev = (l==0) ? bng : bng + (l-1)*192 + 128;
    const float* bPrev = (l==0) ? bnb : bnb + (l-1)*192 + 128;
    k_A<<<G, Blk, 0, stream>>>(smlp, bnaccPrev, gPrev, bPrev,
                               hbuf, hsum + l*64,
                               gruWhh + l*12288, grubhh + l*192,
                               Wqkv + l*12288, bqkv + l*192,
                               gh, Qb, Kb, Vt, (l==0) ? 1 : 0);
    k_attn<<<dim3(2048), dim3(64), 0, stream>>>(Qb, Kb, Vt, Upart, mpart, lpart);
    k_B2<<<G, Blk, 0, stream>>>(hbuf, gh, hsum + l*64, Upart, mpart, lpart,
                                convWg + l*4096, gruWih + l*12288, grubih + l*192,
                                Wo + l*4096, bo + l*64,
                                s1, s2, bnacc + l*384);
    k_C<<<G, Blk, 0, stream>>>(s1, s2, bng + l*192, bnb + l*192,
                               W1 + l*8192, b1 + l*128, W2 + l*8192, b2 + l*64,
                               smlp, bnacc + l*384);
  }

  k_out<<<G, Blk, 0, stream>>>(smlp, bnacc + 4*384, bng + 896, bnb + 896,
                               outW, outb, (float*)d_out);
}

// Round 4
// 612.137 us; speedup vs baseline: 1.9276x; 1.0431x over previous
//
#include <hip/hip_runtime.h>

#define NB 2048
#define HDM 64
#define NLAY 5

typedef __bf16 bf16x8 __attribute__((ext_vector_type(8)));
typedef float v4f __attribute__((ext_vector_type(4)));

__device__ __forceinline__ float sigmoidf_(float x){ return 1.f/(1.f+__expf(-x)); }
__device__ __forceinline__ float tanhfast_(float x){
  x = fminf(fmaxf(x, -15.f), 15.f);
  float e = __expf(2.f*x);
  return (e-1.f)/(e+1.f);
}
__device__ __forceinline__ unsigned short f2b_rne(float f){
  unsigned u = __float_as_uint(f);
  unsigned r = u + 0x7FFFu + ((u>>16)&1u);
  return (unsigned short)(r>>16);
}
__device__ __forceinline__ unsigned pk2(float a, float b){
  unsigned ua = (__float_as_uint(a) + 0x8000u) >> 16;
  unsigned ub = (__float_as_uint(b) + 0x8000u) & 0xFFFF0000u;
  return ua | ub;
}

// ---------------- Kernel: time-embedding + GEMM1 (8-way K-split, 4x4 per thread) ----------
// grid 1024 x 256. TE: rows blk*2 + r (r<2).
// GEMM1: rowgroup rg = blk>>3 (16 rows), K-eighth kq = blk&7 (512 k).
__global__ __launch_bounds__(256) void k_pre(
    const float* __restrict__ x, const float* __restrict__ tt,
    const float* __restrict__ freqs,
    const float* __restrict__ fc1W, const float* __restrict__ fc1b,
    const float* __restrict__ fc2W, const float* __restrict__ fc2b,
    const float* __restrict__ tprojW, const float* __restrict__ tprojb,
    const float* __restrict__ nodeW,
    float* __restrict__ h0p, float* __restrict__ htime,
    float* __restrict__ zero_region)   // hsum(320) + bnacc(1920) contiguous
{
  __shared__ float xsT[256*20];    // transposed x tile [k][row], stride 20; reused as reduce buf
  __shared__ float tb0[128];
  __shared__ float tb1[128];
  const int t = threadIdx.x, blk = blockIdx.x;
  const int r = t>>6, c = t&63;

  if (blk == 0){
    for (int i = t; i < 320 + 1920; i += 256) zero_region[i] = 0.f;
  }

  // ---- time embedding for rows blk*2 + r  (r<2 active) ----
  {
    const int row = blk*2 + (r&1);
    const float tv = tt[row];
    if (r < 2){
      float te[16];
      #pragma unroll
      for (int j=0;j<8;++j){
        float sv, cv;
        __sincosf(6.28318530717958647692f*tv*freqs[j], &sv, &cv);
        te[j]=sv; te[j+8]=cv;
      }
      float a = fc1b[c];
      #pragma unroll
      for (int j=0;j<16;++j) a += te[j]*fc1W[j*64+c];
      tb0[r*64+c] = a*sigmoidf_(a);
    }
    __syncthreads();
    if (r < 2){
      float b2 = fc2b[c];
      #pragma unroll 8
      for (int k=0;k<64;++k) b2 += tb0[r*64+k]*fc2W[k*64+c];
      tb1[r*64+c] = b2;
    }
    __syncthreads();
    if (r < 2){
      float hti = tprojb[c];
      #pragma unroll 8
      for (int k=0;k<64;++k) hti += tb1[r*64+k]*tprojW[k*64+c];
      htime[row*64+c] = hti;
    }
  }

  // ---- GEMM1 partial: rows0..rows0+15, k0..k0+511 ----
  const int rg = blk>>3, kq = blk&7;
  const int rows0 = rg*16, k0 = kq*512;
  const int col4 = (t&15)*4;        // 4 output cols
  const int rq4  = ((t>>4)&3)*4;    // 4 output rows
  const int ksub = (t>>6)*64;       // 64-k slice within 256-k chunk

  float4 a0={0,0,0,0}, a1={0,0,0,0}, a2={0,0,0,0}, a3={0,0,0,0};

  for (int ch=0; ch<2; ++ch){
    __syncthreads();
    // stage x chunk transposed: xsT[k_local][row]
    #pragma unroll
    for (int i=0;i<4;++i){
      int fi = t + 256*i;
      int xr = fi>>6, kk = (fi&63)<<2;
      float4 xv = *(const float4*)&x[(size_t)(rows0+xr)*4096 + k0 + ch*256 + kk];
      xsT[(kk+0)*20+xr]=xv.x; xsT[(kk+1)*20+xr]=xv.y;
      xsT[(kk+2)*20+xr]=xv.z; xsT[(kk+3)*20+xr]=xv.w;
    }
    __syncthreads();
    const float* wp = &nodeW[(size_t)(k0 + ch*256 + ksub)*64 + col4];
    const float* xp = &xsT[ksub*20 + rq4];
    #pragma unroll 8
    for (int kk=0; kk<64; ++kk){
      float4 w  = *(const float4*)&wp[kk*64];
      float4 xr4 = *(const float4*)&xp[kk*20];
      a0.x += xr4.x*w.x; a0.y += xr4.x*w.y; a0.z += xr4.x*w.z; a0.w += xr4.x*w.w;
      a1.x += xr4.y*w.x; a1.y += xr4.y*w.y; a1.z += xr4.y*w.z; a1.w += xr4.y*w.w;
      a2.x += xr4.z*w.x; a2.y += xr4.z*w.y; a2.z += xr4.z*w.z; a2.w += xr4.z*w.w;
      a3.x += xr4.w*w.x; a3.y += xr4.w*w.y; a3.z += xr4.w*w.z; a3.w += xr4.w*w.w;
    }
  }
  // ---- reduce the 4 k-slices via LDS ----
  __syncthreads();
  {
    const int kqi = t>>6;
    *(float4*)&xsT[(kqi*16 + rq4 + 0)*64 + col4] = a0;
    *(float4*)&xsT[(kqi*16 + rq4 + 1)*64 + col4] = a1;
    *(float4*)&xsT[(kqi*16 + rq4 + 2)*64 + col4] = a2;
    *(float4*)&xsT[(kqi*16 + rq4 + 3)*64 + col4] = a3;
  }
  __syncthreads();
  {
    const int row = t>>4, c4 = (t&15)*4;
    float4 s = {0,0,0,0};
    #pragma unroll
    for (int q=0;q<4;++q){
      float4 v = *(const float4*)&xsT[(q*16+row)*64 + c4];
      s.x+=v.x; s.y+=v.y; s.z+=v.z; s.w+=v.w;
    }
    *(float4*)&h0p[(size_t)kq*(NB*HDM) + (rows0+row)*64 + c4] = s;
  }
}

// ---------------- Kernel: assemble h ----------------
__global__ __launch_bounds__(256) void k_assemble(
    const float* __restrict__ h0p, const float* __restrict__ htime,
    const float* __restrict__ nodeb,
    const float* __restrict__ tcatW, const float* __restrict__ tcatb,
    const float* __restrict__ penb, const float* __restrict__ pelW,
    const float* __restrict__ pelb,
    const float* __restrict__ catW, const float* __restrict__ catb,
    float* __restrict__ hbuf)
{
  __shared__ float sa[256];
  __shared__ float sb[256];
  __shared__ float cvec[64];
  const int t = threadIdx.x, blk = blockIdx.x;
  const int r = t>>6, c = t&63;
  const int row = blk*4 + r;

  if (r==0){
    float pl[16];
    #pragma unroll
    for (int j=0;j<16;++j){
      float a = pelb[j];
      for (int w=0;w<20;++w) a += penb[w]*pelW[w*16+j];
      pl[j]=a;
    }
    float a = catb[c];
    #pragma unroll
    for (int j=0;j<16;++j) a += pl[j]*catW[(64+j)*64+c];
    cvec[c]=a;
  }
  float h0 = nodeb[c];
  #pragma unroll
  for (int q=0;q<8;++q) h0 += h0p[(size_t)q*(NB*HDM) + row*64 + c];
  sa[t] = h0;
  sb[t] = htime[row*64+c];
  __syncthreads();
  float a = tcatb[c];
  #pragma unroll 4
  for (int k=0;k<64;++k){
    a += sa[r*64+k]*tcatW[k*64+c];
    a += sb[r*64+k]*tcatW[(64+k)*64+c];
  }
  __syncthreads();
  sa[t] = a;
  __syncthreads();
  float hv = cvec[c];
  #pragma unroll 8
  for (int k=0;k<64;++k) hv += sa[r*64+k]*catW[k*64+c];
  hbuf[row*64+c] = hv;
}

// ---------------- Kernel A (per layer): [bn3 of prev] + hsum + gh + bf16 QKV packs --------
__global__ __launch_bounds__(256) void k_A(
    const float* __restrict__ smlp,
    const float* __restrict__ bnaccPrev,
    const float* __restrict__ gPrev, const float* __restrict__ bPrev,
    float* __restrict__ hbuf, float* __restrict__ hsumL,
    const float* __restrict__ Whh, const float* __restrict__ bhh,
    const float* __restrict__ Wq,  const float* __restrict__ bq,
    float* __restrict__ gh,
    unsigned short* __restrict__ Qb, unsigned short* __restrict__ Kb,
    unsigned short* __restrict__ Vt, int first)
{
  __shared__ float sa[256];
  const int t = threadIdx.x, blk = blockIdx.x;
  const int r = t>>6, c = t&63;
  const int row0 = blk*4;
  const int row = row0 + r;

  float hv;
  if (first){
    hv = hbuf[row*64+c];
  } else {
    float mu = bnaccPrev[256+c]*(1.f/NB);
    float va = bnaccPrev[320+c]*(1.f/NB) - mu*mu;
    hv = gPrev[c]*(smlp[row*64+c]-mu)*rsqrtf(va+1e-5f)+bPrev[c];
    hbuf[row*64+c] = hv;
  }
  sa[t] = hv;
  __syncthreads();
  if (t<64){
    atomicAdd(&hsumL[t], sa[t]+sa[64+t]+sa[128+t]+sa[192+t]);
  }
  // 3 output chains interleaved for load ILP
  int rrA[3], ccA[3];
  float ag[3], aq[3];
  #pragma unroll
  for (int i=0;i<3;++i){
    int idx = t + 256*i;
    rrA[i] = idx/192; ccA[i] = idx - rrA[i]*192;
    ag[i] = bhh[ccA[i]]; aq[i] = bq[ccA[i]];
  }
  #pragma unroll 4
  for (int k=0;k<64;++k){
    #pragma unroll
    for (int i=0;i<3;++i){
      float hk = sa[rrA[i]*64+k];
      ag[i] += hk*Whh[k*192+ccA[i]];
      aq[i] += hk*Wq [k*192+ccA[i]];
    }
  }
  #pragma unroll
  for (int i=0;i<3;++i){
    int rw = row0 + rrA[i], cc = ccA[i];
    gh[(size_t)rw*192+cc] = ag[i];
    float aqv = aq[i];
    if (cc < 64){
      int hd = cc>>4, dh = cc&15;
      size_t base = ((size_t)(hd<<11) + rw)*32;
      Qb[base+dh] = f2b_rne(aqv*0.25f);
      Qb[base+16+dh] = 0;
    } else if (cc < 128){
      int c2 = cc-64, hd = c2>>4, dh = c2&15;
      size_t base = ((size_t)(hd<<11) + rw)*32;
      Kb[base+dh] = f2b_rne(aqv);
      Kb[base+16+dh] = 0;
    } else {
      int c2 = cc-128, hd = c2>>4, dh = c2&15;
      Vt[((size_t)(hd*16+dh))*2048 + rw] = f2b_rne(aqv);
    }
  }
}

// ---------------- Kernel: flash attention, MFMA, K-split in 4 parts ----------------
__global__ __launch_bounds__(64) void k_attn(
    const unsigned short* __restrict__ Qb, const unsigned short* __restrict__ Kb,
    const unsigned short* __restrict__ Vt,
    float* __restrict__ Upart, float* __restrict__ mpart, float* __restrict__ lpart)
{
  __shared__ unsigned short Pl[16*40];
  const int lane = threadIdx.x;
  const int q15 = lane & 15, quad = lane >> 4;
  const int b = blockIdx.x;
  const int qt = b & 127, head = (b>>7)&3, part = b>>9;
  const int qrow = qt*16 + q15;
  const int key00 = part*512;

  const bf16x8 qf = *(const bf16x8*)&Qb[(((size_t)(head<<11))+qrow)*32 + quad*8];
  const unsigned short* Kb_h = Kb + ((size_t)(head<<11))*32;
  const unsigned short* Vrow = Vt + ((size_t)(head*16+q15))*2048;

  v4f O = {0.f,0.f,0.f,0.f};
  float m = -1e30f, lsum = 0.f;

  bf16x8 kf0 = *(const bf16x8*)&Kb_h[(size_t)(key00 + q15)*32 + quad*8];
  bf16x8 kf1 = *(const bf16x8*)&Kb_h[(size_t)(key00 + 16 + q15)*32 + quad*8];
  bf16x8 vf  = *(const bf16x8*)&Vrow[key00 + quad*8];

  for (int c=0; c<16; ++c){
    bf16x8 nk0, nk1, nv;
    if (c < 15){
      int nk = key00 + (c+1)*32;
      nk0 = *(const bf16x8*)&Kb_h[(size_t)(nk + q15)*32 + quad*8];
      nk1 = *(const bf16x8*)&Kb_h[(size_t)(nk + 16 + q15)*32 + quad*8];
      nv  = *(const bf16x8*)&Vrow[nk + quad*8];
    }
    v4f z = {0.f,0.f,0.f,0.f};
    v4f s0 = __builtin_amdgcn_mfma_f32_16x16x32_bf16(kf0, qf, z, 0,0,0);
    v4f s1 = __builtin_amdgcn_mfma_f32_16x16x32_bf16(kf1, qf, z, 0,0,0);
    float cmax = fmaxf(fmaxf(fmaxf(s0[0],s0[1]),fmaxf(s0[2],s0[3])),
                       fmaxf(fmaxf(s1[0],s1[1]),fmaxf(s1[2],s1[3])));
    cmax = fmaxf(cmax, __shfl_xor(cmax,16,64));
    cmax = fmaxf(cmax, __shfl_xor(cmax,32,64));
    float mnew = fmaxf(m, cmax);
    float alpha = __expf(m - mnew);
    float p0=__expf(s0[0]-mnew), p1=__expf(s0[1]-mnew), p2=__expf(s0[2]-mnew), p3=__expf(s0[3]-mnew);
    float p4=__expf(s1[0]-mnew), p5=__expf(s1[1]-mnew), p6=__expf(s1[2]-mnew), p7=__expf(s1[3]-mnew);
    lsum = alpha*lsum + ((p0+p1)+(p2+p3)+((p4+p5)+(p6+p7)));
    m = mnew;
    O[0]*=alpha; O[1]*=alpha; O[2]*=alpha; O[3]*=alpha;
    *(uint2*)&Pl[q15*40 + quad*4]      = make_uint2(pk2(p0,p1), pk2(p2,p3));
    *(uint2*)&Pl[q15*40 + 16 + quad*4] = make_uint2(pk2(p4,p5), pk2(p6,p7));
    __syncthreads();
    bf16x8 pf = *(const bf16x8*)&Pl[q15*40 + quad*8];
    O = __builtin_amdgcn_mfma_f32_16x16x32_bf16(vf, pf, O, 0,0,0);
    kf0 = nk0; kf1 = nk1; vf = nv;
  }
  lsum += __shfl_xor(lsum,16,64);
  lsum += __shfl_xor(lsum,32,64);
  size_t ub = ((size_t)((part*4+head)*2048) + qrow)*16 + quad*4;
  *(float4*)&Upart[ub] = make_float4(O[0],O[1],O[2],O[3]);
  if (quad==0){
    mpart[(size_t)(part*4+head)*2048 + qrow] = m;
    lpart[(size_t)(part*4+head)*2048 + qrow] = lsum;
  }
}

// ---------------- Kernel B2 (per layer): combine partials + o-proj + GRU + bn1/bn2 stats ----
__global__ __launch_bounds__(256) void k_B2(
    const float* __restrict__ hbuf, const float* __restrict__ gh,
    const float* __restrict__ hsumL,
    const float* __restrict__ Upart, const float* __restrict__ mpart,
    const float* __restrict__ lpart,
    const float* __restrict__ Wg,   const float* __restrict__ Wih,
    const float* __restrict__ bih,  const float* __restrict__ Wo,
    const float* __restrict__ bo,
    float* __restrict__ s1, float* __restrict__ s2, float* __restrict__ bnaccL)
{
  __shared__ float sa[256];
  __shared__ float os[256];
  __shared__ float smv_[64];
  __shared__ float sgi[192];
  __shared__ float Sb[512];
  const int t = threadIdx.x, blk = blockIdx.x;
  const int r = t>>6, c = t&63;
  const int row = blk*4 + r;
  const int head = c>>4, dh = c&15;

  if (t<64){
    float a=0.f;
    #pragma unroll 8
    for (int k=0;k<64;++k) a += hsumL[k]*Wg[k*64+t];
    smv_[t]=a;
  }
  sa[t] = hbuf[row*64+c];

  float m0 = mpart[(size_t)(head)*2048+row],    m1 = mpart[(size_t)(4+head)*2048+row];
  float m2 = mpart[(size_t)(8+head)*2048+row],  m3 = mpart[(size_t)(12+head)*2048+row];
  float mm = fmaxf(fmaxf(m0,m1),fmaxf(m2,m3));
  float a0=__expf(m0-mm), a1=__expf(m1-mm), a2=__expf(m2-mm), a3=__expf(m3-mm);
  float ll = a0*lpart[(size_t)(head)*2048+row]   + a1*lpart[(size_t)(4+head)*2048+row]
           + a2*lpart[(size_t)(8+head)*2048+row] + a3*lpart[(size_t)(12+head)*2048+row];
  float uu = a0*Upart[((size_t)(head)*2048+row)*16+dh]    + a1*Upart[((size_t)(4+head)*2048+row)*16+dh]
           + a2*Upart[((size_t)(8+head)*2048+row)*16+dh]  + a3*Upart[((size_t)(12+head)*2048+row)*16+dh];
  os[t] = uu / ll;
  __syncthreads();
  if (t<192){
    float a = bih[t];
    #pragma unroll 8
    for (int k=0;k<64;++k) a += smv_[k]*Wih[k*192+t];
    sgi[t]=a;
  }
  __syncthreads();

  float o2 = bo[c];
  #pragma unroll 8
  for (int k=0;k<64;++k) o2 += os[r*64+k]*Wo[k*64+c];
  float hv = sa[t];
  float s2v = o2 + hv;
  float ir = sgi[c]      + gh[(size_t)row*192+c];
  float iz = sgi[64+c]   + gh[(size_t)row*192+64+c];
  float inn = sgi[128+c];
  float hn  = gh[(size_t)row*192+128+c];
  float rr_ = sigmoidf_(ir);
  float zz  = sigmoidf_(iz);
  float nn  = tanhfast_(inn + rr_*hn);
  float s1v = (1.f-zz)*nn + zz*hv + hv;
  s1[row*64+c] = s1v;
  s2[row*64+c] = s2v;
  Sb[t] = s1v; Sb[256+t] = s2v;
  __syncthreads();
  if (t<64){
    float a=0.f,aq=0.f,b=0.f,bq2=0.f;
    #pragma unroll
    for (int rr=0;rr<4;++rr){
      float v1 = Sb[rr*64+t], v2 = Sb[256+rr*64+t];
      a+=v1; aq+=v1*v1; b+=v2; bq2+=v2*v2;
    }
    atomicAdd(&bnaccL[t],a);     atomicAdd(&bnaccL[64+t],aq);
    atomicAdd(&bnaccL[128+t],b); atomicAdd(&bnaccL[192+t],bq2);
  }
}

// ---------------- Kernel C (per layer): bn1/bn2 apply + MLP + bn3 stats ----------------
__global__ __launch_bounds__(256) void k_C(
    const float* __restrict__ s1, const float* __restrict__ s2,
    const float* __restrict__ bngL, const float* __restrict__ bnbL,
    const float* __restrict__ W1, const float* __restrict__ b1,
    const float* __restrict__ W2, const float* __restrict__ b2,
    float* __restrict__ smlp, float* __restrict__ bnaccL)
{
  __shared__ float sa[256];
  __shared__ float sh[512];
  __shared__ float S2[256];
  const int t = threadIdx.x, blk = blockIdx.x;
  const int r = t>>6, c = t&63;
  const int row = blk*4 + r;

  float mu1 = bnaccL[c]*(1.f/NB);
  float va1 = bnaccL[64+c]*(1.f/NB) - mu1*mu1;
  float mu2 = bnaccL[128+c]*(1.f/NB);
  float va2 = bnaccL[192+c]*(1.f/NB) - mu2*mu2;
  float h1 = bngL[c]*(s1[row*64+c]-mu1)*rsqrtf(va1+1e-5f)+bnbL[c];
  float h2 = bngL[64+c]*(s2[row*64+c]-mu2)*rsqrtf(va2+1e-5f)+bnbL[64+c];
  float sv = h1+h2;
  sa[t]=sv;
  __syncthreads();
  // two output chains interleaved
  {
    const int rr0 = t>>7, hj0 = t&127;
    const int idx1 = t + 256;
    const int rr1 = idx1>>7, hj1 = idx1&127;
    float a0v = b1[hj0], a1v = b1[hj1];
    #pragma unroll 4
    for (int k=0;k<64;++k){
      a0v += sa[rr0*64+k]*W1[k*128+hj0];
      a1v += sa[rr1*64+k]*W1[k*128+hj1];
    }
    sh[t] = fmaxf(a0v, 0.f);
    sh[t+256] = fmaxf(a1v, 0.f);
  }
  __syncthreads();
  float mo = b2[c];
  #pragma unroll 8
  for (int k=0;k<128;++k) mo += sh[r*128+k]*W2[k*64+c];
  float smv2 = sv + mo;
  smlp[row*64+c]=smv2;
  S2[t]=smv2;
  __syncthreads();
  if (t<64){
    float a=0.f,aq=0.f;
    #pragma unroll
    for (int rr=0;rr<4;++rr){ float v=S2[rr*64+t]; a+=v; aq+=v*v; }
    atomicAdd(&bnaccL[256+t],a); atomicAdd(&bnaccL[320+t],aq);
  }
}

// ---------------- Kernel: GEMM2 with fused final bn3 ----------------
__global__ __launch_bounds__(256) void k_out(
  const float* __restrict__ smlp, const float* __restrict__ bnacc4,
  const float* __restrict__ g4, const float* __restrict__ b4,
  const float* __restrict__ outW, const float* __restrict__ outb,
  float* __restrict__ out)
{
  __shared__ float hsT[64*20];
  const int t = threadIdx.x, blk = blockIdx.x;
  const int rg = blk>>2, cg = blk&3;
  const int rows0 = rg*16;
  #pragma unroll
  for (int i=0;i<4;++i){
    int idx = t + 256*i;
    int k = idx&63, rr = idx>>6;
    float mu = bnacc4[256+k]*(1.f/NB);
    float va = bnacc4[320+k]*(1.f/NB)-mu*mu;
    hsT[k*20+rr] = g4[k]*(smlp[(size_t)(rows0+rr)*64+k]-mu)*rsqrtf(va+1e-5f)+b4[k];
  }
  __syncthreads();
  for (int j=0;j<4;++j){
    int cc = cg*1024 + t + 256*j;
    float acc[16];
    float bv = outb[cc];
    #pragma unroll
    for (int rr=0;rr<16;++rr) acc[rr]=bv;
    #pragma unroll 4
    for (int k=0;k<64;++k){
      float w = outW[(size_t)k*4096+cc];
      const float4* hp = (const float4*)&hsT[k*20];
      float4 h0=hp[0], h1=hp[1], h2=hp[2], h3=hp[3];
      acc[0]+=h0.x*w;  acc[1]+=h0.y*w;  acc[2]+=h0.z*w;  acc[3]+=h0.w*w;
      acc[4]+=h1.x*w;  acc[5]+=h1.y*w;  acc[6]+=h1.z*w;  acc[7]+=h1.w*w;
      acc[8]+=h2.x*w;  acc[9]+=h2.y*w;  acc[10]+=h2.z*w; acc[11]+=h2.w*w;
      acc[12]+=h3.x*w; acc[13]+=h3.y*w; acc[14]+=h3.z*w; acc[15]+=h3.w*w;
    }
    #pragma unroll
    for (int rr=0;rr<16;++rr) out[(size_t)(rows0+rr)*4096+cc]=acc[rr];
  }
}

extern "C" void kernel_launch(void* const* d_in, const int* in_sizes, int n_in,
                              void* d_out, int out_size, void* d_ws, size_t ws_size,
                              hipStream_t stream)
{
  (void)in_sizes; (void)n_in; (void)out_size; (void)ws_size;
  const float* x      = (const float*)d_in[0];
  const float* tt     = (const float*)d_in[1];
  const float* freqs  = (const float*)d_in[2];
  const float* fc1W   = (const float*)d_in[3];
  const float* fc1b   = (const float*)d_in[4];
  const float* fc2W   = (const float*)d_in[5];
  const float* fc2b   = (const float*)d_in[6];
  const float* nodeW  = (const float*)d_in[7];
  const float* nodeb  = (const float*)d_in[8];
  const float* tprojW = (const float*)d_in[9];
  const float* tprojb = (const float*)d_in[10];
  const float* tcatW  = (const float*)d_in[11];
  const float* tcatb  = (const float*)d_in[12];
  const float* penb   = (const float*)d_in[14];
  const float* pelW   = (const float*)d_in[15];
  const float* pelb   = (const float*)d_in[16];
  const float* catW   = (const float*)d_in[17];
  const float* catb   = (const float*)d_in[18];
  const float* convWg = (const float*)d_in[19];
  const float* gruWih = (const float*)d_in[20];
  const float* grubih = (const float*)d_in[21];
  const float* gruWhh = (const float*)d_in[22];
  const float* grubhh = (const float*)d_in[23];
  const float* Wqkv   = (const float*)d_in[24];
  const float* bqkv   = (const float*)d_in[25];
  const float* Wo     = (const float*)d_in[26];
  const float* bo     = (const float*)d_in[27];
  const float* bng    = (const float*)d_in[28];
  const float* bnb    = (const float*)d_in[29];
  const float* W1     = (const float*)d_in[30];
  const float* b1     = (const float*)d_in[31];
  const float* W2     = (const float*)d_in[32];
  const float* b2     = (const float*)d_in[33];
  const float* outW   = (const float*)d_in[34];
  const float* outb   = (const float*)d_in[35];

  float* ws = (float*)d_ws;
  float* htime = ws;                  // 131072
  float* hbuf  = htime + 131072;      // 131072
  float* gh    = hbuf + 131072;       // 393216
  float* s1    = gh + 393216;         // 131072
  float* s2    = s1 + 131072;         // 131072
  float* smlp  = s2 + 131072;         // 131072
  float* hsum  = smlp + 131072;       // 320
  float* bnacc = hsum + 320;          // 1920
  float* Upart = bnacc + 1920;        // 524288
  float* mpart = Upart + 524288;      // 32768
  float* lpart = mpart + 32768;       // 32768
  unsigned short* Qb = (unsigned short*)(lpart + 32768);  // 262144 sh
  unsigned short* Kb = Qb + 262144;                       // 262144 sh
  unsigned short* Vt = Kb + 262144;                       // 65536 sh
  // h0p (8 x 2048 x 64 fp32) overlaps Upart..QKV region: disjoint lifetime
  // (written by k_pre, consumed by k_assemble, both before the layer loop)
  float* h0p = Upart;

  dim3 G(512), Blk(256);

  k_pre<<<dim3(1024), Blk, 0, stream>>>(x, tt, freqs, fc1W, fc1b, fc2W, fc2b,
                                        tprojW, tprojb, nodeW, h0p, htime, hsum);

  k_assemble<<<G, Blk, 0, stream>>>(h0p, htime, nodeb, tcatW, tcatb,
                                    penb, pelW, pelb, catW, catb, hbuf);

  for (int l=0; l<NLAY; ++l){
    const float* bnaccPrev = (l==0) ? bnacc : bnacc + (l-1)*384;
    const float* gPrev = (l==0) ? bng : bng + (l-1)*192 + 128;
    const float* bPrev = (l==0) ? bnb : bnb + (l-1)*192 + 128;
    k_A<<<G, Blk, 0, stream>>>(smlp, bnaccPrev, gPrev, bPrev,
                               hbuf, hsum + l*64,
                               gruWhh + l*12288, grubhh + l*192,
                               Wqkv + l*12288, bqkv + l*192,
                               gh, Qb, Kb, Vt, (l==0) ? 1 : 0);
    k_attn<<<dim3(2048), dim3(64), 0, stream>>>(Qb, Kb, Vt, Upart, mpart, lpart);
    k_B2<<<G, Blk, 0, stream>>>(hbuf, gh, hsum + l*64, Upart, mpart, lpart,
                                convWg + l*4096, gruWih + l*12288, grubih + l*192,
                                Wo + l*4096, bo + l*64,
                                s1, s2, bnacc + l*384);
    k_C<<<G, Blk, 0, stream>>>(s1, s2, bng + l*192, bnb + l*192,
                               W1 + l*8192, b1 + l*128, W2 + l*8192, b2 + l*64,
                               smlp, bnacc + l*384);
  }

  k_out<<<G, Blk, 0, stream>>>(smlp, bnacc + 4*384, bng + 896, bnb + 896,
                               outW, outb, (float*)d_out);
}

// Round 5
// 523.483 us; speedup vs baseline: 2.2541x; 1.1694x over previous
//
#include <hip/hip_runtime.h>

#define NB 2048
#define HDM 64
#define NLAY 5

typedef __bf16 bf16x8 __attribute__((ext_vector_type(8)));
typedef float v4f __attribute__((ext_vector_type(4)));

__device__ __forceinline__ float sigmoidf_(float x){ return 1.f/(1.f+__expf(-x)); }
__device__ __forceinline__ float tanhfast_(float x){
  x = fminf(fmaxf(x, -15.f), 15.f);
  float e = __expf(2.f*x);
  return (e-1.f)/(e+1.f);
}
__device__ __forceinline__ unsigned short f2b_rne(float f){
  unsigned u = __float_as_uint(f);
  unsigned r = u + 0x7FFFu + ((u>>16)&1u);
  return (unsigned short)(r>>16);
}
__device__ __forceinline__ unsigned pk2(float a, float b){
  unsigned ua = (__float_as_uint(a) + 0x8000u) >> 16;
  unsigned ub = (__float_as_uint(b) + 0x8000u) & 0xFFFF0000u;
  return ua | ub;
}

// ---------------- Kernel: time-embedding + GEMM1 (8-way K-split, 4x4 per thread) ----------
// grid 1024 x 256. TE: rows blk*2 + r (r<2).
// GEMM1: rowgroup rg = blk>>3 (16 rows), K-eighth kq = blk&7 (512 k).
// x tile staged UNTRANSPOSED, stride 260 (reads: broadcast ds_read_b32, <=2-way = free).
__global__ __launch_bounds__(256) void k_pre(
    const float* __restrict__ x, const float* __restrict__ tt,
    const float* __restrict__ freqs,
    const float* __restrict__ fc1W, const float* __restrict__ fc1b,
    const float* __restrict__ fc2W, const float* __restrict__ fc2b,
    const float* __restrict__ tprojW, const float* __restrict__ tprojb,
    const float* __restrict__ nodeW,
    float* __restrict__ h0p, float* __restrict__ htime,
    float* __restrict__ zero_region)   // hsum(320) + bnacc(1920) contiguous
{
  __shared__ float xs[16*260];     // [row][k] pad-260; reused as reduce buf (needs 4096)
  __shared__ float tb0[128];
  __shared__ float tb1[128];
  const int t = threadIdx.x, blk = blockIdx.x;
  const int r = t>>6, c = t&63;

  if (blk == 0){
    for (int i = t; i < 320 + 1920; i += 256) zero_region[i] = 0.f;
  }

  // ---- time embedding for rows blk*2 + (r&1), r<2 active ----
  {
    const int row = blk*2 + (r&1);
    const float tv = tt[row];
    if (r < 2){
      float te[16];
      #pragma unroll
      for (int j=0;j<8;++j){
        float sv, cv;
        __sincosf(6.28318530717958647692f*tv*freqs[j], &sv, &cv);
        te[j]=sv; te[j+8]=cv;
      }
      float a = fc1b[c];
      #pragma unroll
      for (int j=0;j<16;++j) a += te[j]*fc1W[j*64+c];
      tb0[r*64+c] = a*sigmoidf_(a);
    }
    __syncthreads();
    if (r < 2){
      float b2 = fc2b[c];
      #pragma unroll 8
      for (int k=0;k<64;++k) b2 += tb0[r*64+k]*fc2W[k*64+c];
      tb1[r*64+c] = b2;
    }
    __syncthreads();
    if (r < 2){
      float hti = tprojb[c];
      #pragma unroll 8
      for (int k=0;k<64;++k) hti += tb1[r*64+k]*tprojW[k*64+c];
      htime[row*64+c] = hti;
    }
  }

  // ---- GEMM1 partial: rows0..rows0+15, k0..k0+511 ----
  const int rg = blk>>3, kq = blk&7;
  const int rows0 = rg*16, k0 = kq*512;
  const int col4 = (t&15)*4;        // 4 output cols
  const int rq4  = ((t>>4)&3)*4;    // 4 output rows
  const int ksub = (t>>6)*64;       // 64-k slice within 256-k chunk

  float4 a0={0,0,0,0}, a1={0,0,0,0}, a2={0,0,0,0}, a3={0,0,0,0};

  for (int ch=0; ch<2; ++ch){
    __syncthreads();
    #pragma unroll
    for (int i=0;i<4;++i){
      int fi = t + 256*i;
      int xr = fi>>6, kk = (fi&63)<<2;
      *(float4*)&xs[xr*260+kk] = *(const float4*)&x[(size_t)(rows0+xr)*4096 + k0 + ch*256 + kk];
    }
    __syncthreads();
    const float* wp = &nodeW[(size_t)(k0 + ch*256 + ksub)*64 + col4];
    const float* xp = &xs[rq4*260 + ksub];
    #pragma unroll 8
    for (int kk=0; kk<64; ++kk){
      float4 w  = *(const float4*)&wp[kk*64];
      float x0 = xp[kk];
      float x1 = xp[260+kk];
      float x2 = xp[520+kk];
      float x3 = xp[780+kk];
      a0.x += x0*w.x; a0.y += x0*w.y; a0.z += x0*w.z; a0.w += x0*w.w;
      a1.x += x1*w.x; a1.y += x1*w.y; a1.z += x1*w.z; a1.w += x1*w.w;
      a2.x += x2*w.x; a2.y += x2*w.y; a2.z += x2*w.z; a2.w += x2*w.w;
      a3.x += x3*w.x; a3.y += x3*w.y; a3.z += x3*w.z; a3.w += x3*w.w;
    }
  }
  // ---- reduce the 4 k-slices via LDS ----
  __syncthreads();
  {
    const int kqi = t>>6;
    *(float4*)&xs[(kqi*16 + rq4 + 0)*64 + col4] = a0;
    *(float4*)&xs[(kqi*16 + rq4 + 1)*64 + col4] = a1;
    *(float4*)&xs[(kqi*16 + rq4 + 2)*64 + col4] = a2;
    *(float4*)&xs[(kqi*16 + rq4 + 3)*64 + col4] = a3;
  }
  __syncthreads();
  {
    const int row = t>>4, c4 = (t&15)*4;
    float4 s = {0,0,0,0};
    #pragma unroll
    for (int q=0;q<4;++q){
      float4 v = *(const float4*)&xs[(q*16+row)*64 + c4];
      s.x+=v.x; s.y+=v.y; s.z+=v.z; s.w+=v.w;
    }
    *(float4*)&h0p[(size_t)kq*(NB*HDM) + (rows0+row)*64 + c4] = s;
  }
}

// ---------------- Kernel: assemble h ----------------
__global__ __launch_bounds__(256) void k_assemble(
    const float* __restrict__ h0p, const float* __restrict__ htime,
    const float* __restrict__ nodeb,
    const float* __restrict__ tcatW, const float* __restrict__ tcatb,
    const float* __restrict__ penb, const float* __restrict__ pelW,
    const float* __restrict__ pelb,
    const float* __restrict__ catW, const float* __restrict__ catb,
    float* __restrict__ hbuf)
{
  __shared__ float sa[256];
  __shared__ float sb[256];
  __shared__ float cvec[64];
  const int t = threadIdx.x, blk = blockIdx.x;
  const int r = t>>6, c = t&63;
  const int row = blk*4 + r;

  if (r==0){
    float pl[16];
    #pragma unroll
    for (int j=0;j<16;++j){
      float a = pelb[j];
      for (int w=0;w<20;++w) a += penb[w]*pelW[w*16+j];
      pl[j]=a;
    }
    float a = catb[c];
    #pragma unroll
    for (int j=0;j<16;++j) a += pl[j]*catW[(64+j)*64+c];
    cvec[c]=a;
  }
  float h0 = nodeb[c];
  #pragma unroll
  for (int q=0;q<8;++q) h0 += h0p[(size_t)q*(NB*HDM) + row*64 + c];
  sa[t] = h0;
  sb[t] = htime[row*64+c];
  __syncthreads();
  float a = tcatb[c];
  #pragma unroll 4
  for (int k=0;k<64;++k){
    a += sa[r*64+k]*tcatW[k*64+c];
    a += sb[r*64+k]*tcatW[(64+k)*64+c];
  }
  __syncthreads();
  sa[t] = a;
  __syncthreads();
  float hv = cvec[c];
  #pragma unroll 8
  for (int k=0;k<64;++k) hv += sa[r*64+k]*catW[k*64+c];
  hbuf[row*64+c] = hv;
}

// ---------------- Kernel A (per layer): [bn3 prev] + hsum + gh + bf16 QKV packs ----------
// grid 256 x 256: 8 rows/block; threads t<192 own column cc for all 8 rows (8 FMA / load).
__global__ __launch_bounds__(256) void k_A(
    const float* __restrict__ smlp,
    const float* __restrict__ bnaccPrev,
    const float* __restrict__ gPrev, const float* __restrict__ bPrev,
    float* __restrict__ hbuf, float* __restrict__ hsumL,
    const float* __restrict__ Whh, const float* __restrict__ bhh,
    const float* __restrict__ Wq,  const float* __restrict__ bq,
    float* __restrict__ gh,
    unsigned short* __restrict__ Qb, unsigned short* __restrict__ Kb,
    unsigned short* __restrict__ Vt, int first)
{
  __shared__ float sa[8*64];
  const int t = threadIdx.x, blk = blockIdx.x;
  const int row0 = blk*8;

  #pragma unroll
  for (int i=0;i<2;++i){
    int idx = t + 256*i;
    int rl = idx>>6, c = idx&63;
    int row = row0 + rl;
    float hv;
    if (first){
      hv = hbuf[row*64+c];
    } else {
      float mu = bnaccPrev[256+c]*(1.f/NB);
      float va = bnaccPrev[320+c]*(1.f/NB) - mu*mu;
      hv = gPrev[c]*(smlp[row*64+c]-mu)*rsqrtf(va+1e-5f)+bPrev[c];
      hbuf[row*64+c] = hv;
    }
    sa[idx] = hv;
  }
  __syncthreads();
  if (t<64){
    float s = 0.f;
    #pragma unroll
    for (int rl=0;rl<8;++rl) s += sa[rl*64+t];
    atomicAdd(&hsumL[t], s);
  }
  if (t < 192){
    const int cc = t;
    float ag[8], aq[8];
    float bh = bhh[cc], bq_ = bq[cc];
    #pragma unroll
    for (int rl=0;rl<8;++rl){ ag[rl]=bh; aq[rl]=bq_; }
    #pragma unroll 4
    for (int k=0;k<64;++k){
      float wh = Whh[k*192+cc];
      float wq = Wq [k*192+cc];
      #pragma unroll
      for (int rl=0;rl<8;++rl){
        float hk = sa[rl*64+k];
        ag[rl] += hk*wh;
        aq[rl] += hk*wq;
      }
    }
    #pragma unroll
    for (int rl=0;rl<8;++rl){
      int rw = row0 + rl;
      gh[(size_t)rw*192+cc] = ag[rl];
      float aqv = aq[rl];
      if (cc < 64){
        int hd = cc>>4, dh = cc&15;
        size_t base = ((size_t)(hd<<11) + rw)*32;
        Qb[base+dh] = f2b_rne(aqv*0.25f);
        Qb[base+16+dh] = 0;
      } else if (cc < 128){
        int c2 = cc-64, hd = c2>>4, dh = c2&15;
        size_t base = ((size_t)(hd<<11) + rw)*32;
        Kb[base+dh] = f2b_rne(aqv);
        Kb[base+16+dh] = 0;
      } else {
        int c2 = cc-128, hd = c2>>4, dh = c2&15;
        Vt[((size_t)(hd*16+dh))*2048 + rw] = f2b_rne(aqv);
      }
    }
  }
}

// ---------------- Kernel: flash attention, MFMA; 4 K-parts per block, in-block merge ------
// grid 512 x 256. block: qt = b&127, head = b>>7. wave w = part (512 keys each).
__global__ __launch_bounds__(256) void k_attn(
    const unsigned short* __restrict__ Qb, const unsigned short* __restrict__ Kb,
    const unsigned short* __restrict__ Vt,
    float* __restrict__ o_out)
{
  __shared__ unsigned short Pl[4*640];   // per-wave P^T panel, q-row stride 40
  __shared__ float Os[4*272];            // per-part O, [q*17+dh]
  __shared__ float ms[64], ls[64];       // [part*16+q]
  const int t = threadIdx.x;
  const int w = t>>6, lane = t&63;
  const int q15 = lane & 15, quad = lane >> 4;
  const int b = blockIdx.x;
  const int qt = b & 127, head = b>>7;
  const int qrow = qt*16 + q15;
  const int key00 = w*512;
  unsigned short* Plw = &Pl[w*640];

  const bf16x8 qf = *(const bf16x8*)&Qb[(((size_t)(head<<11))+qrow)*32 + quad*8];
  const unsigned short* Kb_h = Kb + ((size_t)(head<<11))*32;
  const unsigned short* Vrow = Vt + ((size_t)(head*16+q15))*2048;

  v4f O = {0.f,0.f,0.f,0.f};
  float m = -1e30f, lsum = 0.f;

  bf16x8 kf0 = *(const bf16x8*)&Kb_h[(size_t)(key00 + q15)*32 + quad*8];
  bf16x8 kf1 = *(const bf16x8*)&Kb_h[(size_t)(key00 + 16 + q15)*32 + quad*8];
  bf16x8 vf  = *(const bf16x8*)&Vrow[key00 + quad*8];

  for (int c=0; c<16; ++c){
    bf16x8 nk0, nk1, nv;
    if (c < 15){
      int nk = key00 + (c+1)*32;
      nk0 = *(const bf16x8*)&Kb_h[(size_t)(nk + q15)*32 + quad*8];
      nk1 = *(const bf16x8*)&Kb_h[(size_t)(nk + 16 + q15)*32 + quad*8];
      nv  = *(const bf16x8*)&Vrow[nk + quad*8];
    }
    v4f z = {0.f,0.f,0.f,0.f};
    v4f s0 = __builtin_amdgcn_mfma_f32_16x16x32_bf16(kf0, qf, z, 0,0,0);
    v4f s1 = __builtin_amdgcn_mfma_f32_16x16x32_bf16(kf1, qf, z, 0,0,0);
    float cmax = fmaxf(fmaxf(fmaxf(s0[0],s0[1]),fmaxf(s0[2],s0[3])),
                       fmaxf(fmaxf(s1[0],s1[1]),fmaxf(s1[2],s1[3])));
    cmax = fmaxf(cmax, __shfl_xor(cmax,16,64));
    cmax = fmaxf(cmax, __shfl_xor(cmax,32,64));
    float mnew = fmaxf(m, cmax);
    float alpha = __expf(m - mnew);
    float p0=__expf(s0[0]-mnew), p1=__expf(s0[1]-mnew), p2=__expf(s0[2]-mnew), p3=__expf(s0[3]-mnew);
    float p4=__expf(s1[0]-mnew), p5=__expf(s1[1]-mnew), p6=__expf(s1[2]-mnew), p7=__expf(s1[3]-mnew);
    lsum = alpha*lsum + ((p0+p1)+(p2+p3)+((p4+p5)+(p6+p7)));
    m = mnew;
    O[0]*=alpha; O[1]*=alpha; O[2]*=alpha; O[3]*=alpha;
    // intra-wave LDS repack (single-wave: in-order DS pipe + explicit waitcnt barrier)
    *(uint2*)&Plw[q15*40 + quad*4]      = make_uint2(pk2(p0,p1), pk2(p2,p3));
    *(uint2*)&Plw[q15*40 + 16 + quad*4] = make_uint2(pk2(p4,p5), pk2(p6,p7));
    asm volatile("s_waitcnt lgkmcnt(0)" ::: "memory");
    bf16x8 pf = *(const bf16x8*)&Plw[q15*40 + quad*8];
    O = __builtin_amdgcn_mfma_f32_16x16x32_bf16(vf, pf, O, 0,0,0);
    kf0 = nk0; kf1 = nk1; vf = nv;
  }
  lsum += __shfl_xor(lsum,16,64);
  lsum += __shfl_xor(lsum,32,64);
  // publish per-part state
  #pragma unroll
  for (int j=0;j<4;++j) Os[w*272 + q15*17 + quad*4 + j] = O[j];
  if (quad==0){ ms[w*16+q15]=m; ls[w*16+q15]=lsum; }
  __syncthreads();
  // merge 4 parts; thread t: dh = t&15, q = t>>4
  {
    const int dh = t&15, q = t>>4;
    float m0=ms[q], m1=ms[16+q], m2=ms[32+q], m3=ms[48+q];
    float mm = fmaxf(fmaxf(m0,m1),fmaxf(m2,m3));
    float a0=__expf(m0-mm), a1=__expf(m1-mm), a2=__expf(m2-mm), a3=__expf(m3-mm);
    float ll = a0*ls[q]+a1*ls[16+q]+a2*ls[32+q]+a3*ls[48+q];
    float oo = a0*Os[q*17+dh] + a1*Os[272+q*17+dh] + a2*Os[544+q*17+dh] + a3*Os[816+q*17+dh];
    o_out[(size_t)(qt*16+q)*64 + head*16 + dh] = oo / ll;
  }
}

// ---------------- Kernel B2 (per layer): o-proj + GRU + bn1/bn2 stats ----------------
// grid 256 x 256: 8 rows/block.
__global__ __launch_bounds__(256) void k_B2(
    const float* __restrict__ hbuf, const float* __restrict__ gh,
    const float* __restrict__ hsumL, const float* __restrict__ o_out,
    const float* __restrict__ Wg,   const float* __restrict__ Wih,
    const float* __restrict__ bih,  const float* __restrict__ Wo,
    const float* __restrict__ bo,
    float* __restrict__ s1, float* __restrict__ s2, float* __restrict__ bnaccL)
{
  __shared__ float sa[8*64];
  __shared__ float os[8*64];
  __shared__ float smv_[64];
  __shared__ float sgi[192];
  __shared__ float Sb1[8*64];
  __shared__ float Sb2[8*64];
  const int t = threadIdx.x, blk = blockIdx.x;
  const int row0 = blk*8;

  if (t<64){
    float a=0.f;
    #pragma unroll 8
    for (int k=0;k<64;++k) a += hsumL[k]*Wg[k*64+t];
    smv_[t]=a;
  }
  #pragma unroll
  for (int i=0;i<2;++i){
    int idx = t + 256*i;
    int rl = idx>>6, c = idx&63;
    sa[idx] = hbuf[(size_t)(row0+rl)*64+c];
    os[idx] = o_out[(size_t)(row0+rl)*64+c];
  }
  __syncthreads();
  if (t<192){
    float a = bih[t];
    #pragma unroll 8
    for (int k=0;k<64;++k) a += smv_[k]*Wih[k*192+t];
    sgi[t]=a;
  }
  __syncthreads();

  // o-proj: thread (c = t&63, rg = t>>6) does rows 2rg, 2rg+1
  const int c = t&63, rg = t>>6;
  float o2a = bo[c], o2b = bo[c];
  #pragma unroll 4
  for (int k=0;k<64;++k){
    float w = Wo[k*64+c];
    o2a += os[(rg*2  )*64+k]*w;
    o2b += os[(rg*2+1)*64+k]*w;
  }
  #pragma unroll
  for (int i=0;i<2;++i){
    int rl = rg*2 + i;
    int row = row0 + rl;
    float o2 = i ? o2b : o2a;
    float hv = sa[rl*64+c];
    float s2v = o2 + hv;
    float ir = sgi[c]      + gh[(size_t)row*192+c];
    float iz = sgi[64+c]   + gh[(size_t)row*192+64+c];
    float inn = sgi[128+c];
    float hn  = gh[(size_t)row*192+128+c];
    float rr_ = sigmoidf_(ir);
    float zz  = sigmoidf_(iz);
    float nn  = tanhfast_(inn + rr_*hn);
    float s1v = (1.f-zz)*nn + zz*hv + hv;   // hc + h
    s1[(size_t)row*64+c] = s1v;
    s2[(size_t)row*64+c] = s2v;
    Sb1[rl*64+c] = s1v;
    Sb2[rl*64+c] = s2v;
  }
  __syncthreads();
  if (t<64){
    float a=0.f,aq=0.f,b=0.f,bq2=0.f;
    #pragma unroll
    for (int rl=0;rl<8;++rl){
      float v1 = Sb1[rl*64+t], v2 = Sb2[rl*64+t];
      a+=v1; aq+=v1*v1; b+=v2; bq2+=v2*v2;
    }
    atomicAdd(&bnaccL[t],a);     atomicAdd(&bnaccL[64+t],aq);
    atomicAdd(&bnaccL[128+t],b); atomicAdd(&bnaccL[192+t],bq2);
  }
}

// ---------------- Kernel C (per layer): bn1/bn2 apply + MLP + bn3 stats ----------------
// grid 256 x 256: 8 rows/block.
__global__ __launch_bounds__(256) void k_C(
    const float* __restrict__ s1, const float* __restrict__ s2,
    const float* __restrict__ bngL, const float* __restrict__ bnbL,
    const float* __restrict__ W1, const float* __restrict__ b1,
    const float* __restrict__ W2, const float* __restrict__ b2,
    float* __restrict__ smlp, float* __restrict__ bnaccL)
{
  __shared__ float sa[8*64];
  __shared__ float sh[8*128];
  __shared__ float S2[8*64];
  const int t = threadIdx.x, blk = blockIdx.x;
  const int row0 = blk*8;

  #pragma unroll
  for (int i=0;i<2;++i){
    int idx = t + 256*i;
    int rl = idx>>6, c = idx&63;
    int row = row0 + rl;
    float mu1 = bnaccL[c]*(1.f/NB);
    float va1 = bnaccL[64+c]*(1.f/NB) - mu1*mu1;
    float mu2 = bnaccL[128+c]*(1.f/NB);
    float va2 = bnaccL[192+c]*(1.f/NB) - mu2*mu2;
    float h1 = bngL[c]*(s1[(size_t)row*64+c]-mu1)*rsqrtf(va1+1e-5f)+bnbL[c];
    float h2 = bngL[64+c]*(s2[(size_t)row*64+c]-mu2)*rsqrtf(va2+1e-5f)+bnbL[64+c];
    sa[idx] = h1+h2;
  }
  __syncthreads();
  // W1: thread (hj = t&127, rgq = t>>7) does rows rgq*4 .. +3
  {
    const int hj = t&127, rgq = t>>7;
    float a0v=b1[hj], a1v=b1[hj], a2v=b1[hj], a3v=b1[hj];
    #pragma unroll 4
    for (int k=0;k<64;++k){
      float w = W1[k*128+hj];
      a0v += sa[(rgq*4  )*64+k]*w;
      a1v += sa[(rgq*4+1)*64+k]*w;
      a2v += sa[(rgq*4+2)*64+k]*w;
      a3v += sa[(rgq*4+3)*64+k]*w;
    }
    sh[(rgq*4  )*128+hj] = fmaxf(a0v,0.f);
    sh[(rgq*4+1)*128+hj] = fmaxf(a1v,0.f);
    sh[(rgq*4+2)*128+hj] = fmaxf(a2v,0.f);
    sh[(rgq*4+3)*128+hj] = fmaxf(a3v,0.f);
  }
  __syncthreads();
  // W2: thread (c = t&63, rg = t>>6) does rows 2rg, 2rg+1
  {
    const int c = t&63, rg = t>>6;
    float moa = b2[c], mob = b2[c];
    #pragma unroll 4
    for (int k=0;k<128;++k){
      float w = W2[k*64+c];
      moa += sh[(rg*2  )*128+k]*w;
      mob += sh[(rg*2+1)*128+k]*w;
    }
    #pragma unroll
    for (int i=0;i<2;++i){
      int rl = rg*2+i;
      float smv2 = sa[rl*64+c] + (i ? mob : moa);
      smlp[(size_t)(row0+rl)*64+c] = smv2;
      S2[rl*64+c] = smv2;
    }
  }
  __syncthreads();
  if (t<64){
    float a=0.f,aq=0.f;
    #pragma unroll
    for (int rl=0;rl<8;++rl){ float v=S2[rl*64+t]; a+=v; aq+=v*v; }
    atomicAdd(&bnaccL[256+t],a); atomicAdd(&bnaccL[320+t],aq);
  }
}

// ---------------- Kernel: GEMM2 with fused final bn3 ----------------
// grid 512 x 256: rowgroup = blk>>2 (16 rows), colgroup = blk&3; thread = 4 cols x 16 rows.
__global__ __launch_bounds__(256) void k_out(
  const float* __restrict__ smlp, const float* __restrict__ bnacc4,
  const float* __restrict__ g4, const float* __restrict__ b4,
  const float* __restrict__ outW, const float* __restrict__ outb,
  float* __restrict__ out)
{
  __shared__ float hsT[64*20];
  const int t = threadIdx.x, blk = blockIdx.x;
  const int rg = blk>>2, cg = blk&3;
  const int rows0 = rg*16;
  #pragma unroll
  for (int i=0;i<4;++i){
    int idx = t + 256*i;
    int k = idx&63, rr = idx>>6;
    float mu = bnacc4[256+k]*(1.f/NB);
    float va = bnacc4[320+k]*(1.f/NB)-mu*mu;
    hsT[k*20+rr] = g4[k]*(smlp[(size_t)(rows0+rr)*64+k]-mu)*rsqrtf(va+1e-5f)+b4[k];
  }
  __syncthreads();
  const int cc = cg*1024 + t*4;
  float4 acc[16];
  {
    float4 bv = *(const float4*)&outb[cc];
    #pragma unroll
    for (int rr=0;rr<16;++rr) acc[rr]=bv;
  }
  #pragma unroll 4
  for (int k=0;k<64;++k){
    float4 w = *(const float4*)&outW[(size_t)k*4096+cc];
    const float4* hp = (const float4*)&hsT[k*20];
    float4 h0=hp[0], h1=hp[1], h2=hp[2], h3=hp[3];
    acc[0].x+=h0.x*w.x;  acc[0].y+=h0.x*w.y;  acc[0].z+=h0.x*w.z;  acc[0].w+=h0.x*w.w;
    acc[1].x+=h0.y*w.x;  acc[1].y+=h0.y*w.y;  acc[1].z+=h0.y*w.z;  acc[1].w+=h0.y*w.w;
    acc[2].x+=h0.z*w.x;  acc[2].y+=h0.z*w.y;  acc[2].z+=h0.z*w.z;  acc[2].w+=h0.z*w.w;
    acc[3].x+=h0.w*w.x;  acc[3].y+=h0.w*w.y;  acc[3].z+=h0.w*w.z;  acc[3].w+=h0.w*w.w;
    acc[4].x+=h1.x*w.x;  acc[4].y+=h1.x*w.y;  acc[4].z+=h1.x*w.z;  acc[4].w+=h1.x*w.w;
    acc[5].x+=h1.y*w.x;  acc[5].y+=h1.y*w.y;  acc[5].z+=h1.y*w.z;  acc[5].w+=h1.y*w.w;
    acc[6].x+=h1.z*w.x;  acc[6].y+=h1.z*w.y;  acc[6].z+=h1.z*w.z;  acc[6].w+=h1.z*w.w;
    acc[7].x+=h1.w*w.x;  acc[7].y+=h1.w*w.y;  acc[7].z+=h1.w*w.z;  acc[7].w+=h1.w*w.w;
    acc[8].x+=h2.x*w.x;  acc[8].y+=h2.x*w.y;  acc[8].z+=h2.x*w.z;  acc[8].w+=h2.x*w.w;
    acc[9].x+=h2.y*w.x;  acc[9].y+=h2.y*w.y;  acc[9].z+=h2.y*w.z;  acc[9].w+=h2.y*w.w;
    acc[10].x+=h2.z*w.x; acc[10].y+=h2.z*w.y; acc[10].z+=h2.z*w.z; acc[10].w+=h2.z*w.w;
    acc[11].x+=h2.w*w.x; acc[11].y+=h2.w*w.y; acc[11].z+=h2.w*w.z; acc[11].w+=h2.w*w.w;
    acc[12].x+=h3.x*w.x; acc[12].y+=h3.x*w.y; acc[12].z+=h3.x*w.z; acc[12].w+=h3.x*w.w;
    acc[13].x+=h3.y*w.x; acc[13].y+=h3.y*w.y; acc[13].z+=h3.y*w.z; acc[13].w+=h3.y*w.w;
    acc[14].x+=h3.z*w.x; acc[14].y+=h3.z*w.y; acc[14].z+=h3.z*w.z; acc[14].w+=h3.z*w.w;
    acc[15].x+=h3.w*w.x; acc[15].y+=h3.w*w.y; acc[15].z+=h3.w*w.z; acc[15].w+=h3.w*w.w;
  }
  #pragma unroll
  for (int rr=0;rr<16;++rr)
    *(float4*)&out[(size_t)(rows0+rr)*4096+cc] = acc[rr];
}

extern "C" void kernel_launch(void* const* d_in, const int* in_sizes, int n_in,
                              void* d_out, int out_size, void* d_ws, size_t ws_size,
                              hipStream_t stream)
{
  (void)in_sizes; (void)n_in; (void)out_size; (void)ws_size;
  const float* x      = (const float*)d_in[0];
  const float* tt     = (const float*)d_in[1];
  const float* freqs  = (const float*)d_in[2];
  const float* fc1W   = (const float*)d_in[3];
  const float* fc1b   = (const float*)d_in[4];
  const float* fc2W   = (const float*)d_in[5];
  const float* fc2b   = (const float*)d_in[6];
  const float* nodeW  = (const float*)d_in[7];
  const float* nodeb  = (const float*)d_in[8];
  const float* tprojW = (const float*)d_in[9];
  const float* tprojb = (const float*)d_in[10];
  const float* tcatW  = (const float*)d_in[11];
  const float* tcatb  = (const float*)d_in[12];
  const float* penb   = (const float*)d_in[14];
  const float* pelW   = (const float*)d_in[15];
  const float* pelb   = (const float*)d_in[16];
  const float* catW   = (const float*)d_in[17];
  const float* catb   = (const float*)d_in[18];
  const float* convWg = (const float*)d_in[19];
  const float* gruWih = (const float*)d_in[20];
  const float* grubih = (const float*)d_in[21];
  const float* gruWhh = (const float*)d_in[22];
  const float* grubhh = (const float*)d_in[23];
  const float* Wqkv   = (const float*)d_in[24];
  const float* bqkv   = (const float*)d_in[25];
  const float* Wo     = (const float*)d_in[26];
  const float* bo     = (const float*)d_in[27];
  const float* bng    = (const float*)d_in[28];
  const float* bnb    = (const float*)d_in[29];
  const float* W1     = (const float*)d_in[30];
  const float* b1     = (const float*)d_in[31];
  const float* W2     = (const float*)d_in[32];
  const float* b2     = (const float*)d_in[33];
  const float* outW   = (const float*)d_in[34];
  const float* outb   = (const float*)d_in[35];

  float* ws = (float*)d_ws;
  float* htime = ws;                  // 131072
  float* hbuf  = htime + 131072;      // 131072
  float* gh    = hbuf + 131072;       // 393216
  float* s1    = gh + 393216;         // 131072
  float* s2    = s1 + 131072;         // 131072
  float* smlp  = s2 + 131072;         // 131072
  float* o_out = smlp + 131072;       // 131072
  float* hsum  = o_out + 131072;      // 320
  float* bnacc = hsum + 320;          // 1920
  unsigned short* Qb = (unsigned short*)(bnacc + 1920);   // 262144 sh
  unsigned short* Kb = Qb + 262144;                       // 262144 sh
  unsigned short* Vt = Kb + 262144;                       // 65536 sh
  float* h0p  = (float*)(Vt + 65536); // 8*2048*64 = 1048576

  dim3 Blk(256);

  k_pre<<<dim3(1024), Blk, 0, stream>>>(x, tt, freqs, fc1W, fc1b, fc2W, fc2b,
                                        tprojW, tprojb, nodeW, h0p, htime, hsum);

  k_assemble<<<dim3(512), Blk, 0, stream>>>(h0p, htime, nodeb, tcatW, tcatb,
                                            penb, pelW, pelb, catW, catb, hbuf);

  for (int l=0; l<NLAY; ++l){
    const float* bnaccPrev = (l==0) ? bnacc : bnacc + (l-1)*384;
    const float* gPrev = (l==0) ? bng : bng + (l-1)*192 + 128;
    const float* bPrev = (l==0) ? bnb : bnb + (l-1)*192 + 128;
    k_A<<<dim3(256), Blk, 0, stream>>>(smlp, bnaccPrev, gPrev, bPrev,
                                       hbuf, hsum + l*64,
                                       gruWhh + l*12288, grubhh + l*192,
                                       Wqkv + l*12288, bqkv + l*192,
                                       gh, Qb, Kb, Vt, (l==0) ? 1 : 0);
    k_attn<<<dim3(512), Blk, 0, stream>>>(Qb, Kb, Vt, o_out);
    k_B2<<<dim3(256), Blk, 0, stream>>>(hbuf, gh, hsum + l*64, o_out,
                                        convWg + l*4096, gruWih + l*12288, grubih + l*192,
                                        Wo + l*4096, bo + l*64,
                                        s1, s2, bnacc + l*384);
    k_C<<<dim3(256), Blk, 0, stream>>>(s1, s2, bng + l*192, bnb + l*192,
                                       W1 + l*8192, b1 + l*128, W2 + l*8192, b2 + l*64,
                                       smlp, bnacc + l*384);
  }

  k_out<<<dim3(512), Blk, 0, stream>>>(smlp, bnacc + 4*384, bng + 896, bnb + 896,
                                       outW, outb, (float*)d_out);
}